// Round 3
// baseline (28576.224 us; speedup 1.0000x reference)
//
#include <hip/hip_runtime.h>
#include <math.h>

// =====================================================================
// Note_VQVAE forward, MI355X, round 3: persistent cooperative recurrent
// kernels (768 launches -> 2). bf16x3-split MFMA GEMMs as round 2.
// Team barriers: h_t[b,:] depends only on h_{t-1}[b,:], so only blocks
// sharing a b-tile sync (8 teams x 32 blocks). Logits now deterministic
// (per-jt partials, fixed-order reduce) instead of f32 atomics.
// =====================================================================

#define DI __device__ __forceinline__

// ---------------- workspace layout (float offsets) ----------------
#define O_HF   ((size_t)0)
#define O_HB   ((size_t)131072)
#define O_H1   ((size_t)262144)
#define O_H2   ((size_t)393216)
#define O_WEFF ((size_t)524288)
#define O_BEFF ((size_t)551936)
#define O_BNS  ((size_t)555008)
#define O_ESQ  ((size_t)560640)
#define O_HIST ((size_t)562688)
#define O_RED  ((size_t)564736)
#define O_LOG  ((size_t)564752)     // (unused now)
#define O_IDX  ((size_t)567056)
#define O_ZT   ((size_t)575248)
#define O_QT   ((size_t)1623824)
#define O_C2   ((size_t)2672400)
#define O_C1   ((size_t)6866704)
#define O_WT1  ((size_t)15255312)
#define O_WT2  ((size_t)17352464)
#define O_WT3  ((size_t)18401040)
#define O_WTD1 ((size_t)18466576)
#define O_WTD2 ((size_t)18728720)
#define O_YS   ((size_t)19253008)
#define O_D1   O_YS
#define O_DEC  (O_YS + (size_t)8388608)

// team-barrier counters: 16 uints overlaid on conv1-out region.
// enc slots [0..8) zeroed by esq_kern (before encoder; conv1 runs after);
// dec slots [8..16) re-zeroed by split_dec_kern (C1 dead by then).
#define O_CTR  O_C1
// decoder logits partials: 2 x [32 jt][128 b x 9] overlaid on dead zt.
#define O_PLOG O_ZT

#define ESOFF ((size_t)2672400)
#define DSOFF ((size_t)36030224)

#define BN0S 0
#define BN0T 1024
#define BN1S 2048
#define BN1T 2560
#define BN2S 3072
#define BN2T 3584
#define DB1S 4096
#define DB1T 4608
#define DB2S 5120
#define DB2T 5376

#define OUT_NR   0
#define OUT_QZ   294912
#define OUT_LOSS 1343488
#define OUT_CMT  1343489
#define OUT_IDX  1343490
#define OUT_PERP 1351682

DI float sigm(float x){ return 1.0f/(1.0f + expf(-x)); }

typedef __attribute__((ext_vector_type(8))) short s8v;
typedef __attribute__((ext_vector_type(4))) float f32x4;

DI f32x4 MF(s8v a, s8v b, f32x4 c){
  return __builtin_amdgcn_mfma_f32_16x16x32_bf16(a, b, c, 0, 0, 0);
}
DI s8v LD8(const unsigned short* p){ return *(const s8v*)p; }

DI void split3(float x, unsigned short& o0, unsigned short& o1, unsigned short& o2){
  unsigned u0 = __float_as_uint(x);
  unsigned h0 = (u0 + 0x7fffu + ((u0>>16)&1u)) >> 16;
  float x1 = x - __uint_as_float(h0<<16);
  unsigned u1 = __float_as_uint(x1);
  unsigned h1 = (u1 + 0x7fffu + ((u1>>16)&1u)) >> 16;
  float x2 = x1 - __uint_as_float(h1<<16);
  unsigned u2 = __float_as_uint(x2);
  unsigned h2 = (u2 + 0x7fffu + ((u2>>16)&1u)) >> 16;
  o0 = (unsigned short)h0; o1 = (unsigned short)h1; o2 = (unsigned short)h2;
}

#define MF8(A0,A1,A2,Q0,Q1,Q2,C0,C1) \
  C0 = MF(A0,Q0,C0); C1 = MF(A0,Q1,C1); \
  C0 = MF(A1,Q1,C0); C1 = MF(A1,Q0,C1); \
  C0 = MF(A0,Q2,C0); C1 = MF(A2,Q0,C1); \
  C0 = MF(A2,Q1,C0); C1 = MF(A1,Q2,C1);

#define FMA44 \
  acc[0][0] += a4.x*b4.x; acc[0][1] += a4.x*b4.y; acc[0][2] += a4.x*b4.z; acc[0][3] += a4.x*b4.w; \
  acc[1][0] += a4.y*b4.x; acc[1][1] += a4.y*b4.y; acc[1][2] += a4.y*b4.z; acc[1][3] += a4.y*b4.w; \
  acc[2][0] += a4.z*b4.x; acc[2][1] += a4.z*b4.y; acc[2][2] += a4.z*b4.z; acc[2][3] += a4.z*b4.w; \
  acc[3][0] += a4.w*b4.x; acc[3][1] += a4.w*b4.y; acc[3][2] += a4.w*b4.z; acc[3][3] += a4.w*b4.w;

// team barrier: writer wb-L2 fence, relaxed agent spin (no per-poll inv),
// one acquire fence after release. Counters are monotonic (no reset race).
DI void team_barrier(unsigned* c, unsigned target){
  __syncthreads();
  if (threadIdx.x == 0){
    __threadfence();                    // write-back L2 (release)
    atomicAdd(c, 1u);
    while (__hip_atomic_load(c, __ATOMIC_RELAXED, __HIP_MEMORY_SCOPE_AGENT) < target)
      __builtin_amdgcn_s_sleep(1);
    __threadfence();                    // invalidate L1/L2 (acquire)
  }
  __syncthreads();
}

// ---------------- weight transposes into ws (convs) ----------------
__global__ void trans_kern(const float* __restrict__ c1w, const float* __restrict__ c2w,
                           const float* __restrict__ c3w, const float* __restrict__ ct1w,
                           const float* __restrict__ ct2w, float* __restrict__ ws){
  const int A1 = 2097152, A2 = 3145728, A3 = 3211264, A4 = 3473408, A5 = 3997696;
  for (int i = blockIdx.x*256 + threadIdx.x; i < A5; i += gridDim.x*256){
    if (i < A1){
      int j = i; int oc = j & 511; int t = j >> 9; int ic = t & 1023; int k = t >> 10;
      ws[O_WT1 + j] = c1w[((size_t)oc*1024 + ic)*4 + k];
    } else if (i < A2){
      int j = i - A1; int oc = j & 511; int t = j >> 9; int ic = t & 511; int k = t >> 9;
      ws[O_WT2 + j] = c2w[((size_t)oc*512 + ic)*4 + k];
    } else if (i < A3){
      int j = i - A2; int oc = j & 127; int ic = j >> 7;
      ws[O_WT3 + j] = c3w[(size_t)oc*512 + ic];
    } else if (i < A4){
      int j = i - A3; int oc = j & 511; int t = j >> 9; int ic = t & 127; int k = t >> 7;
      ws[O_WTD1 + j] = ct1w[((size_t)ic*512 + oc)*4 + k];
    } else {
      int j = i - A4; int oc = j & 255; int t = j >> 8; int ic = t & 511; int k = t >> 9;
      ws[O_WTD2 + j] = ct2w[((size_t)ic*256 + oc)*4 + k];
    }
  }
}

// ---------------- BN scale/shift precompute ----------------
__global__ void bn_kern(const float* g0,const float* b0,const float* m0,const float* v0,
                        const float* g1,const float* b1,const float* m1,const float* v1,
                        const float* g2,const float* b2,const float* m2,const float* v2,
                        const float* gd1,const float* bd1,const float* md1,const float* vd1,
                        const float* gd2,const float* bd2,const float* md2,const float* vd2,
                        float* __restrict__ bns){
  int i = blockIdx.x*256 + threadIdx.x;
  if (i >= 2816) return;
  const float *g,*b,*m,*v; int c, so, to;
  if (i < 1024){ g=g0;b=b0;m=m0;v=v0;c=i;so=BN0S;to=BN0T; }
  else if (i < 1536){ g=g1;b=b1;m=m1;v=v1;c=i-1024;so=BN1S;to=BN1T; }
  else if (i < 2048){ g=g2;b=b2;m=m2;v=v2;c=i-1536;so=BN2S;to=BN2T; }
  else if (i < 2560){ g=gd1;b=bd1;m=md1;v=vd1;c=i-2048;so=DB1S;to=DB1T; }
  else              { g=gd2;b=bd2;m=md2;v=vd2;c=i-2560;so=DB2S;to=DB2T; }
  float s = g[c]*rsqrtf(v[c] + 1e-5f);
  bns[so + c] = s;
  bns[to + c] = b[c] - m[c]*s;
}

// ---------------- hid / decoder-h1 init + enc h splits ----------------
__global__ __launch_bounds__(256) void init_kern(const float* __restrict__ se,
    const float* __restrict__ ehw, const float* __restrict__ ehb,
    const float* __restrict__ dhw, const float* __restrict__ dhb, float* __restrict__ ws){
  int idx = blockIdx.x*256 + threadIdx.x;
  int n = idx & 1023, b = idx >> 10;
  const float* w; float bias;
  if (n < 512){ w = ehw + (size_t)n*256; bias = ehb[n]; }
  else        { w = dhw + (size_t)(n-512)*256; bias = dhb[n-512]; }
  const float* sp = se + (size_t)b*256;
  float acc = bias;
  for (int k = 0; k < 256; ++k) acc += sp[k]*w[k];
  if (n < 512){
    ws[O_HF + 65536 + b*512 + n] = acc;
    ws[O_HB + 65536 + b*512 + n] = acc;
    unsigned short s0,s1,s2; split3(acc, s0,s1,s2);
    unsigned short* esh = (unsigned short*)(ws + ESOFF) + 4718592;
    int off = 196608 + b*512 + n;
    esh[off] = s0; esh[off+65536] = s1; esh[off+131072] = s2;
    esh[393216+off] = s0; esh[393216+off+65536] = s1; esh[393216+off+131072] = s2;
  } else {
    ws[O_H1 + 65536 + b*512 + (n-512)] = acc;
  }
}

// ---------------- Weff = wih @ ifw,  beff = wih @ ifb + bih ----------------
__global__ __launch_bounds__(256) void weff_kern(const float* __restrict__ gfwih,
    const float* __restrict__ gfbih, const float* __restrict__ gbwih, const float* __restrict__ gbbih,
    const float* __restrict__ ifw, const float* __restrict__ ifb, float* __restrict__ ws){
  int idx = blockIdx.x*256 + threadIdx.x;
  if (idx >= 30720) return;
  int dir = idx / 15360; int r = idx - dir*15360;
  int j3 = r / 10; int d = r - j3*10;
  const float* wih = dir ? gbwih : gfwih;
  float acc = 0.f;
  if (d < 9){
    for (int k = 0; k < 512; ++k) acc += wih[(size_t)j3*512 + k]*ifw[k*9 + d];
    ws[O_WEFF + dir*13824 + j3*9 + d] = acc;
  } else {
    for (int k = 0; k < 512; ++k) acc += wih[(size_t)j3*512 + k]*ifb[k];
    acc += (dir ? gbbih : gfbih)[j3];
    ws[O_BEFF + dir*1536 + j3] = acc;
  }
}

// ---------------- |embed|^2 + zero hist/red + enc/dec counters ----------------
__global__ __launch_bounds__(256) void esq_kern(const float* __restrict__ embed, float* __restrict__ ws){
  int e = blockIdx.x*256 + threadIdx.x;
  float acc = 0.f;
  for (int c = 0; c < 128; ++c){ float t = embed[(size_t)e*128 + c]; acc += t*t; }
  ws[O_ESQ + e] = acc;
  if (blockIdx.x == 0){
    for (int i = threadIdx.x; i < 2048; i += 256) ws[O_HIST + i] = 0.f;
    if (threadIdx.x < 16) ws[O_RED + threadIdx.x] = 0.f;
    if (threadIdx.x < 16) ((unsigned*)(ws + O_CTR))[threadIdx.x] = 0u;
  }
}

// ---------------- encoder recurrent weight splits ----------------
__global__ void split_w_kern(const float* __restrict__ gfwhh,
    const float* __restrict__ gbwhh, float* __restrict__ ws){
  unsigned short* es = (unsigned short*)(ws + ESOFF);
  for (int i = blockIdx.x*256 + threadIdx.x; i < 1572864; i += gridDim.x*256){
    int half = i >= 786432;
    int idx = i - (half ? 786432 : 0);
    float x = half ? gbwhh[idx] : gfwhh[idx];
    unsigned short s0,s1,s2; split3(x,s0,s1,s2);
    unsigned short* d = es + (half ? 2359296 : 0);
    d[idx] = s0; d[idx+786432] = s1; d[idx+1572864] = s2;
  }
}

// ---------------- decoder weight splits + h1-init splits (after conv1) ----
__global__ void split_w2_kern(const float* __restrict__ g1wih, const float* __restrict__ g1whh,
    const float* __restrict__ g2wih, const float* __restrict__ g2whh, float* __restrict__ ws){
  unsigned short* dsb = (unsigned short*)(ws + DSOFF);
  const int total = 393216 + 3*786432 + 65536;
  for (int i = blockIdx.x*256 + threadIdx.x; i < total; i += gridDim.x*256){
    float x; unsigned short* d; int off, stride;
    if (i < 393216){
      int row = i>>8, k = i&255;
      x = g1wih[(size_t)row*274 + 9 + k]; d = dsb; off = i; stride = 393216;
    } else if (i < 1179648){
      int idx = i-393216; x = g1whh[idx]; d = dsb + 1179648; off = idx; stride = 786432;
    } else if (i < 1966080){
      int idx = i-1179648; x = g2wih[idx]; d = dsb + 3538944; off = idx; stride = 786432;
    } else if (i < 2752512){
      int idx = i-1966080; x = g2whh[idx]; d = dsb + 5898240; off = idx; stride = 786432;
    } else {
      int idx = i-2752512; x = ws[O_H1 + 65536 + idx];
      d = dsb + 8257536 + 196608; off = idx; stride = 65536;
    }
    unsigned short s0,s1,s2; split3(x,s0,s1,s2);
    d[off] = s0; d[off+stride] = s1; d[off+2*stride] = s2;
  }
}

// ---------------- dec-input splits + dec counter zero ----------------
__global__ void split_dec_kern(float* __restrict__ ws){
  unsigned short* decs = (unsigned short*)(ws + ESOFF);
  const float* dec = ws + O_DEC;
  if (blockIdx.x == 0 && threadIdx.x < 8)
    ((unsigned*)(ws + O_CTR))[8 + threadIdx.x] = 0u;
  for (int i = blockIdx.x*256 + threadIdx.x; i < 8388608; i += gridDim.x*256){
    unsigned short s0,s1,s2; split3(dec[i],s0,s1,s2);
    decs[i] = s0; decs[i+8388608] = s1; decs[i+16777216] = s2;
  }
}

// ---------------- PERSISTENT encoder bi-GRU (cooperative) ----------------
// 256 blocks: dir(2) x bt(4: 32 rows) x jt(32: 16 j). team = (dir,bt), 32 blocks.
__global__ __launch_bounds__(256) void enc_persist(
    float* __restrict__ ws, const float* __restrict__ note,
    const float* __restrict__ gfbhh, const float* __restrict__ gbbhh){
  int bi = blockIdx.x;
  int dir = bi>>7, bt = (bi>>5)&3, jt = bi&31;
  int b0 = bt*32, j0 = jt*16;
  int tid = threadIdx.x, w = tid>>6, l = tid&63;
  int m = w&1, kh = w>>1;
  unsigned* ctr = (unsigned*)(ws + O_CTR) + (dir*4 + bt);
  float* hbase = ws + (dir? O_HB : O_HF);
  unsigned short* esh = (unsigned short*)(ws + ESOFF) + 4718592 + dir*393216;
  const unsigned short* wsp = (const unsigned short*)(ws + ESOFF) + dir*2359296;
  const float* weff = ws + O_WEFF + dir*13824;
  const float* beff = ws + O_BEFF + dir*1536;
  const float* bhh = dir? gbbhh : gfbhh;
  const float* bns = ws + O_BNS;
  float* ys = ws + O_YS;
  __shared__ float red[3072];

  // per-thread epilogue constants (j fixed across all steps)
  int je = j0 + (l&15);
  float wef[3][9], bef3[3], bhh3[3], bsc, bsh;
  #pragma unroll
  for (int g = 0; g < 3; ++g){
    bef3[g] = beff[g*512 + je];
    #pragma unroll
    for (int d = 0; d < 9; ++d) wef[g][d] = weff[(size_t)(g*512+je)*9 + d];
    bhh3[g] = bhh[g*512 + je];
  }
  { int c = dir*512 + je; bsc = bns[BN0S + c]; bsh = bns[BN0T + c]; }

  const unsigned short* bb = wsp + (size_t)(j0 + (l&15))*512 + kh*256 + ((l>>4)<<3);

  #pragma unroll 1
  for (int step = 0; step < 256; ++step){
    int pb = (step+1)&1, cb = step&1;
    const float* hprev = hbase + (size_t)pb*65536;
    float*       hnext = hbase + (size_t)cb*65536;
    const unsigned short* hsp = esh + pb*196608;
    unsigned short*       hsn = esh + cb*196608;

    const unsigned short* ab = hsp + (size_t)(b0 + m*16 + (l&15))*512 + kh*256 + ((l>>4)<<3);
    f32x4 z4 = {0.f,0.f,0.f,0.f};
    f32x4 acc[3][2] = {{z4,z4},{z4,z4},{z4,z4}};
    #pragma unroll
    for (int kt = 0; kt < 8; ++kt){
      s8v a0 = LD8(ab + kt*32);
      s8v a1 = LD8(ab + 65536 + kt*32);
      s8v a2 = LD8(ab + 131072 + kt*32);
      #pragma unroll
      for (int g = 0; g < 3; ++g){
        const unsigned short* bp = bb + g*262144 + kt*32;
        s8v q0 = LD8(bp);
        s8v q1 = LD8(bp + 786432);
        s8v q2 = LD8(bp + 1572864);
        MF8(a0,a1,a2, q0,q1,q2, acc[g][0], acc[g][1])
      }
    }
    #pragma unroll
    for (int g = 0; g < 3; ++g){
      f32x4 s = acc[g][0] + acc[g][1];
      #pragma unroll
      for (int i = 0; i < 4; ++i) red[((w*3+g)<<8) + (i<<6) + l] = s[i];
    }
    __syncthreads();
    int t = dir ? 255-step : step;
    #pragma unroll
    for (int ii = 0; ii < 2; ++ii){
      int i = kh*2 + ii;
      int b = b0 + m*16 + ((l>>4)<<2) + i;
      float Y[3];
      #pragma unroll
      for (int g = 0; g < 3; ++g)
        Y[g] = red[((m*3+g)<<8)+(i<<6)+l] + red[((m*3+g+6)<<8)+(i<<6)+l];
      const float* nt = note + ((size_t)b*256 + t)*9;
      float gi[3];
      #pragma unroll
      for (int g = 0; g < 3; ++g){
        float a = bef3[g];
        #pragma unroll
        for (int d = 0; d < 9; ++d) a += nt[d]*wef[g][d];
        gi[g] = a;
      }
      float hpv = hprev[(size_t)b*512 + je];
      float r = sigm(gi[0] + Y[0] + bhh3[0]);
      float zz = sigm(gi[1] + Y[1] + bhh3[1]);
      float nn = tanhf(gi[2] + r*(Y[2] + bhh3[2]));
      float h = (1.f - zz)*nn + zz*hpv;
      hnext[(size_t)b*512 + je] = h;
      unsigned short s0,s1,s2; split3(h, s0,s1,s2);
      int off = b*512 + je;
      hsn[off] = s0; hsn[off+65536] = s1; hsn[off+131072] = s2;
      int c = dir*512 + je;
      ys[((size_t)b*256 + t)*1024 + c] = h*bsc + bsh;
    }
    team_barrier(ctr, 32u*(step+1));
  }
}

// ---------------- PERSISTENT decoder 2xGRU + logits (cooperative) ----------
// 256 blocks: bt(8: 16 rows) x jt(32: 16 j). team = bt, 32 blocks, 2 barriers/step.
__global__ __launch_bounds__(256) void dec_persist(
    float* __restrict__ ws, const float* __restrict__ skel, const float* __restrict__ sr,
    const float* __restrict__ w1ih, const float* __restrict__ b1ih,
    const float* __restrict__ b1hh, const float* __restrict__ nfb,
    const float* __restrict__ b2ih, const float* __restrict__ b2hh,
    const float* __restrict__ nfw, float* __restrict__ dout){
  int bi = blockIdx.x;
  int bt = bi>>5, jt = bi&31;
  int b0 = bt*16, j0 = jt*16;
  int tid = threadIdx.x, w = tid>>6, l = tid&63;
  int kh = w;
  unsigned* ctr = (unsigned*)(ws + O_CTR) + 8 + bt;
  unsigned short* dsb = (unsigned short*)(ws + DSOFF);
  const unsigned short* decs = (const unsigned short*)(ws + ESOFF);
  const unsigned short* w1d = dsb;
  const unsigned short* w1h = dsb + 1179648;
  const unsigned short* w2i = dsb + 3538944;
  const unsigned short* w2h = dsb + 5898240;
  float* plog = ws + O_PLOG;
  __shared__ float fbs[144], ssh[144];
  __shared__ float red[6144];
  __shared__ float hsm[256];

  #pragma unroll 1
  for (int step = 0; step < 256; ++step){
    int pb = (step+1)&1, cb = step&1;
    const float* h1p = ws + O_H1 + (size_t)pb*65536;
    float*       h1n = ws + O_H1 + (size_t)cb*65536;
    const unsigned short* h1sp = dsb + 8257536 + pb*196608;
    unsigned short*       h1sn = dsb + 8257536 + cb*196608;

    // ======== phase A: GRU1 ========
    if (tid < 144){
      int bb = tid/9, d = tid - bb*9; int b = b0 + bb;
      float fv = 0.f;
      if (step > 0){
        float lg = nfb[d];
        const float* pl = plog + (size_t)pb*36864 + b*9 + d;
        #pragma unroll
        for (int q = 0; q < 32; ++q) lg += pl[q*1152];
        if (jt == 0) dout[OUT_NR + (size_t)b*2304 + (step-1)*9 + d] = lg;
        fv = (sigm(lg) - sr[(size_t)(step-1)*1152 + b*9 + d]) > 0.f ? 1.f : 0.f;
      }
      fbs[tid] = fv;
      ssh[tid] = skel[((size_t)b*256 + step)*9 + d];
    }
    f32x4 z4 = {0.f,0.f,0.f,0.f};
    f32x4 gia[3][2] = {{z4,z4},{z4,z4},{z4,z4}};
    f32x4 gha[3][2] = {{z4,z4},{z4,z4},{z4,z4}};
    {
      const unsigned short* ab = decs + (size_t)(b0 + (l&15))*65536 + step*256 + kh*64 + ((l>>4)<<3);
      const unsigned short* bbp = w1d + (size_t)(j0 + (l&15))*256 + kh*64 + ((l>>4)<<3);
      #pragma unroll
      for (int kt = 0; kt < 2; ++kt){
        s8v a0 = LD8(ab + kt*32);
        s8v a1 = LD8(ab + 8388608 + kt*32);
        s8v a2 = LD8(ab + 16777216 + kt*32);
        #pragma unroll
        for (int g = 0; g < 3; ++g){
          const unsigned short* bp = bbp + g*131072 + kt*32;
          s8v q0 = LD8(bp);
          s8v q1 = LD8(bp + 393216);
          s8v q2 = LD8(bp + 786432);
          MF8(a0,a1,a2, q0,q1,q2, gia[g][0], gia[g][1])
        }
      }
    }
    {
      const unsigned short* ab = h1sp + (size_t)(b0 + (l&15))*512 + kh*128 + ((l>>4)<<3);
      const unsigned short* bbp = w1h + (size_t)(j0 + (l&15))*512 + kh*128 + ((l>>4)<<3);
      #pragma unroll
      for (int kt = 0; kt < 4; ++kt){
        s8v a0 = LD8(ab + kt*32);
        s8v a1 = LD8(ab + 65536 + kt*32);
        s8v a2 = LD8(ab + 131072 + kt*32);
        #pragma unroll
        for (int g = 0; g < 3; ++g){
          const unsigned short* bp = bbp + g*262144 + kt*32;
          s8v q0 = LD8(bp);
          s8v q1 = LD8(bp + 786432);
          s8v q2 = LD8(bp + 1572864);
          MF8(a0,a1,a2, q0,q1,q2, gha[g][0], gha[g][1])
        }
      }
    }
    #pragma unroll
    for (int g = 0; g < 3; ++g){
      f32x4 s = gia[g][0] + gia[g][1];
      f32x4 t = gha[g][0] + gha[g][1];
      #pragma unroll
      for (int i = 0; i < 4; ++i){
        red[((w*6+g)<<8) + (i<<6) + l] = s[i];
        red[((w*6+g+3)<<8) + (i<<6) + l] = t[i];
      }
    }
    __syncthreads();
    {
      int i = w;
      int b = b0 + ((l>>4)<<2) + i;
      int j = j0 + (l&15);
      float GI[3], GH[3];
      #pragma unroll
      for (int pg = 0; pg < 3; ++pg){
        float a = 0.f, c = 0.f;
        #pragma unroll
        for (int ww = 0; ww < 4; ++ww){
          a += red[((ww*6+pg)<<8)+(i<<6)+l];
          c += red[((ww*6+pg+3)<<8)+(i<<6)+l];
        }
        GI[pg] = a; GH[pg] = c;
      }
      int bb = b - b0;
      #pragma unroll
      for (int g = 0; g < 3; ++g){
        const float* wr = w1ih + (size_t)(g*512+j)*274;
        float a = GI[g] + b1ih[g*512+j];
        #pragma unroll
        for (int d = 0; d < 9; ++d) a += fbs[bb*9+d]*wr[d] + ssh[bb*9+d]*wr[265+d];
        GI[g] = a;
      }
      float hpv = h1p[(size_t)b*512 + j];
      float r = sigm(GI[0] + GH[0] + b1hh[j]);
      float zz = sigm(GI[1] + GH[1] + b1hh[512+j]);
      float nn = tanhf(GI[2] + r*(GH[2] + b1hh[1024+j]));
      float h = (1.f-zz)*nn + zz*hpv;
      h1n[(size_t)b*512 + j] = h;
      unsigned short s0,s1,s2; split3(h,s0,s1,s2);
      int off = b*512 + j;
      h1sn[off] = s0; h1sn[off+65536] = s1; h1sn[off+131072] = s2;
    }
    team_barrier(ctr, 64u*step + 32u);

    // ======== phase B: GRU2 + logits partials ========
    const float* h2p = (step==0) ? h1n : ws + O_H2 + (size_t)pb*65536;
    float*       h2n = ws + O_H2 + (size_t)cb*65536;
    const unsigned short* h2sp = (step==0) ? (const unsigned short*)h1sn
                                           : dsb + 8650752 + pb*196608;
    unsigned short* h2sn = dsb + 8650752 + cb*196608;

    f32x4 kia[3][2] = {{z4,z4},{z4,z4},{z4,z4}};
    f32x4 kha[3][2] = {{z4,z4},{z4,z4},{z4,z4}};
    {
      const unsigned short* ab = h1sn + (size_t)(b0 + (l&15))*512 + kh*128 + ((l>>4)<<3);
      const unsigned short* bbp = w2i + (size_t)(j0 + (l&15))*512 + kh*128 + ((l>>4)<<3);
      #pragma unroll
      for (int kt = 0; kt < 4; ++kt){
        s8v a0 = LD8(ab + kt*32);
        s8v a1 = LD8(ab + 65536 + kt*32);
        s8v a2 = LD8(ab + 131072 + kt*32);
        #pragma unroll
        for (int g = 0; g < 3; ++g){
          const unsigned short* bp = bbp + g*262144 + kt*32;
          s8v q0 = LD8(bp);
          s8v q1 = LD8(bp + 786432);
          s8v q2 = LD8(bp + 1572864);
          MF8(a0,a1,a2, q0,q1,q2, kia[g][0], kia[g][1])
        }
      }
    }
    {
      const unsigned short* ab = h2sp + (size_t)(b0 + (l&15))*512 + kh*128 + ((l>>4)<<3);
      const unsigned short* bbp = w2h + (size_t)(j0 + (l&15))*512 + kh*128 + ((l>>4)<<3);
      #pragma unroll
      for (int kt = 0; kt < 4; ++kt){
        s8v a0 = LD8(ab + kt*32);
        s8v a1 = LD8(ab + 65536 + kt*32);
        s8v a2 = LD8(ab + 131072 + kt*32);
        #pragma unroll
        for (int g = 0; g < 3; ++g){
          const unsigned short* bp = bbp + g*262144 + kt*32;
          s8v q0 = LD8(bp);
          s8v q1 = LD8(bp + 786432);
          s8v q2 = LD8(bp + 1572864);
          MF8(a0,a1,a2, q0,q1,q2, kha[g][0], kha[g][1])
        }
      }
    }
    #pragma unroll
    for (int g = 0; g < 3; ++g){
      f32x4 s = kia[g][0] + kia[g][1];
      f32x4 t = kha[g][0] + kha[g][1];
      #pragma unroll
      for (int i = 0; i < 4; ++i){
        red[((w*6+g)<<8) + (i<<6) + l] = s[i];
        red[((w*6+g+3)<<8) + (i<<6) + l] = t[i];
      }
    }
    __syncthreads();
    {
      int i = w;
      int b = b0 + ((l>>4)<<2) + i;
      int j = j0 + (l&15);
      float GI[3], GH[3];
      #pragma unroll
      for (int pg = 0; pg < 3; ++pg){
        float a = 0.f, c = 0.f;
        #pragma unroll
        for (int ww = 0; ww < 4; ++ww){
          a += red[((ww*6+pg)<<8)+(i<<6)+l];
          c += red[((ww*6+pg+3)<<8)+(i<<6)+l];
        }
        GI[pg] = a; GH[pg] = c;
      }
      float hpv = h2p[(size_t)b*512 + j];
      float r = sigm(GI[0] + b2ih[j] + GH[0] + b2hh[j]);
      float zz = sigm(GI[1] + b2ih[512+j] + GH[1] + b2hh[512+j]);
      float nn = tanhf(GI[2] + b2ih[1024+j] + r*(GH[2] + b2hh[1024+j]));
      float h = (1.f-zz)*nn + zz*hpv;
      h2n[(size_t)b*512 + j] = h;
      unsigned short s0,s1,s2; split3(h,s0,s1,s2);
      int off = b*512 + j;
      h2sn[off] = s0; h2sn[off+65536] = s1; h2sn[off+131072] = s2;
      hsm[(b-b0)*16 + (j-j0)] = h;
    }
    __syncthreads();
    if (tid < 144){
      int bq = tid/9, d = tid - bq*9;
      float v = 0.f;
      #pragma unroll
      for (int jl = 0; jl < 16; ++jl) v += hsm[bq*16+jl]*nfw[(size_t)d*512 + j0 + jl];
      plog[(size_t)cb*36864 + jt*1152 + (b0+bq)*9 + d] = v;
    }
    team_barrier(ctr, 64u*step + 64u);
  }
  // final flush: t=255 logits (step 255 buffer cb=1)
  if (jt == 0 && tid < 144){
    int bb = tid/9, d = tid - bb*9; int b = b0 + bb;
    float lg = nfb[d];
    const float* pl = plog + 36864 + b*9 + d;
    #pragma unroll
    for (int q = 0; q < 32; ++q) lg += pl[q*1152];
    dout[OUT_NR + (size_t)b*2304 + 255*9 + d] = lg;
  }
}

// ---------------- conv1 ----------------
__global__ __launch_bounds__(256) void conv1_kern(const float* __restrict__ ysb,
    const float* __restrict__ wt, const float* __restrict__ cb,
    const float* __restrict__ bns, float* __restrict__ outp){
  int gm = blockIdx.x, gn = blockIdx.y;
  int b = gm >> 1, ot0 = (gm & 1) << 6, oc0 = gn << 6;
  int tid = threadIdx.x, tx = tid & 15, ty = tid >> 4;
  __shared__ __align__(16) float As[32*68];
  __shared__ __align__(16) float Bs[32*68];
  float acc[4][4] = {};
  for (int k = 0; k < 4; ++k){
    for (int ic0 = 0; ic0 < 1024; ic0 += 32){
      #pragma unroll
      for (int rr = 0; rr < 8; ++rr){
        int e = rr*256 + tid; int m = e >> 5, ic = e & 31;
        int tin = ((ot0 + m) << 1) + k - 1;
        float v = 0.f;
        if ((unsigned)tin < 256u) v = ysb[((size_t)b*256 + tin)*1024 + ic0 + ic];
        As[ic*68 + m] = v;
      }
      #pragma unroll
      for (int rr = 0; rr < 8; ++rr){
        int e = rr*256 + tid; int oc = e & 63, ic = e >> 6;
        Bs[ic*68 + oc] = wt[((size_t)k*1024 + ic0 + ic)*512 + oc0 + oc];
      }
      __syncthreads();
      #pragma unroll
      for (int kk = 0; kk < 32; ++kk){
        float4 a4 = *(const float4*)&As[kk*68 + ty*4];
        float4 b4 = *(const float4*)&Bs[kk*68 + tx*4];
        FMA44
      }
      __syncthreads();
    }
  }
  #pragma unroll
  for (int i = 0; i < 4; ++i){
    int ot = ot0 + ty*4 + i;
    #pragma unroll
    for (int jj = 0; jj < 4; ++jj){
      int oc = oc0 + tx*4 + jj;
      float v = acc[i][jj] + cb[oc];
      v = v*bns[BN1S + oc] + bns[BN1T + oc];
      v = v > 0.f ? v : 0.2f*v;
      outp[((size_t)b*128 + ot)*512 + oc] = v;
    }
  }
}

// ---------------- conv2 ----------------
__global__ __launch_bounds__(256) void conv2_kern(const float* __restrict__ c1o,
    const float* __restrict__ wt, const float* __restrict__ cb,
    const float* __restrict__ bns, float* __restrict__ outp){
  int b = blockIdx.x, oc0 = blockIdx.y << 6;
  int tid = threadIdx.x, tx = tid & 15, ty = tid >> 4;
  __shared__ __align__(16) float As[32*68];
  __shared__ __align__(16) float Bs[32*68];
  float acc[4][4] = {};
  for (int k = 0; k < 4; ++k){
    for (int ic0 = 0; ic0 < 512; ic0 += 32){
      #pragma unroll
      for (int rr = 0; rr < 8; ++rr){
        int e = rr*256 + tid; int m = e >> 5, ic = e & 31;
        int tin = (m << 1) + k - 1;
        float v = 0.f;
        if ((unsigned)tin < 128u) v = c1o[((size_t)b*128 + tin)*512 + ic0 + ic];
        As[ic*68 + m] = v;
      }
      #pragma unroll
      for (int rr = 0; rr < 8; ++rr){
        int e = rr*256 + tid; int oc = e & 63, ic = e >> 6;
        Bs[ic*68 + oc] = wt[((size_t)k*512 + ic0 + ic)*512 + oc0 + oc];
      }
      __syncthreads();
      #pragma unroll
      for (int kk = 0; kk < 32; ++kk){
        float4 a4 = *(const float4*)&As[kk*68 + ty*4];
        float4 b4 = *(const float4*)&Bs[kk*68 + tx*4];
        FMA44
      }
      __syncthreads();
    }
  }
  #pragma unroll
  for (int i = 0; i < 4; ++i){
    int ot = ty*4 + i;
    #pragma unroll
    for (int jj = 0; jj < 4; ++jj){
      int oc = oc0 + tx*4 + jj;
      float v = acc[i][jj] + cb[oc];
      v = v*bns[BN2S + oc] + bns[BN2T + oc];
      v = v > 0.f ? v : 0.2f*v;
      outp[((size_t)b*64 + ot)*512 + oc] = v;
    }
  }
}

// ---------------- conv3 ----------------
__global__ __launch_bounds__(256) void conv3_kern(const float* __restrict__ c2o,
    const float* __restrict__ wt, const float* __restrict__ cb, float* __restrict__ zt){
  int row0 = blockIdx.x << 6, oc0 = blockIdx.y << 6;
  int tid = threadIdx.x, tx = tid & 15, ty = tid >> 4;
  __shared__ __align__(16) float As[32*68];
  __shared__ __align__(16) float Bs[32*68];
  float acc[4][4] = {};
  for (int ic0 = 0; ic0 < 512; ic0 += 32){
    #pragma unroll
    for (int rr = 0; rr < 8; ++rr){
      int e = rr*256 + tid; int m = e >> 5, ic = e & 31;
      As[ic*68 + m] = c2o[((size_t)(row0 + m))*512 + ic0 + ic];
    }
    #pragma unroll
    for (int rr = 0; rr < 8; ++rr){
      int e = rr*256 + tid; int oc = e & 63, ic = e >> 6;
      Bs[ic*68 + oc] = wt[(size_t)(ic0 + ic)*128 + oc0 + oc];
    }
    __syncthreads();
    #pragma unroll
    for (int kk = 0; kk < 32; ++kk){
      float4 a4 = *(const float4*)&As[kk*68 + ty*4];
      float4 b4 = *(const float4*)&Bs[kk*68 + tx*4];
      FMA44
    }
    __syncthreads();
  }
  #pragma unroll
  for (int i = 0; i < 4; ++i){
    int row = row0 + ty*4 + i;
    #pragma unroll
    for (int jj = 0; jj < 4; ++jj){
      int oc = oc0 + tx*4 + jj;
      zt[(size_t)row*128 + oc] = acc[i][jj] + cb[oc];
    }
  }
}

// ---------------- VQ argmin ----------------
__global__ __launch_bounds__(256) void vq_kern(const float* __restrict__ zt,
    const float* __restrict__ esq, const float* __restrict__ embed,
    int* __restrict__ idxp, float* __restrict__ hist, float* __restrict__ dout){
  int r0 = blockIdx.x * 8;
  int tid = threadIdx.x;
  int r = tid >> 5, el = tid & 31;
  __shared__ __align__(16) float zsh[1024];
  __shared__ __align__(16) float esh[4096];
  __shared__ float rv[256]; __shared__ int ri[256];
  for (int idx = tid; idx < 1024; idx += 256) zsh[idx] = zt[(size_t)r0*128 + idx];
  float minv = 3.4e38f; int mini = 0;
  for (int e0 = 0; e0 < 2048; e0 += 32){
    for (int idx = tid; idx < 4096; idx += 256){
      int ee = idx >> 7, c = idx & 127;
      esh[ee*128 + ((((c >> 2) ^ (ee & 31)) & 31) << 2) + (c & 3)] = embed[(size_t)(e0 + ee)*128 + c];
    }
    __syncthreads();
    float dot = 0.f;
    #pragma unroll
    for (int c0 = 0; c0 < 128; c0 += 4){
      float4 zq = *(const float4*)&zsh[r*128 + c0];
      float4 e4 = *(const float4*)&esh[el*128 + ((((c0 >> 2) ^ (el & 31)) & 31) << 2)];
      dot += zq.x*e4.x + zq.y*e4.y + zq.z*e4.z + zq.w*e4.w;
    }
    float d = esq[e0 + el] - 2.f*dot;
    if (d < minv){ minv = d; mini = e0 + el; }
    __syncthreads();
  }
  rv[tid] = minv; ri[tid] = mini;
  __syncthreads();
  for (int off = 16; off > 0; off >>= 1){
    if (el < off){
      float ov = rv[tid + off]; int oi = ri[tid + off];
      if (ov < rv[tid] || (ov == rv[tid] && oi < ri[tid])){ rv[tid] = ov; ri[tid] = oi; }
    }
    __syncthreads();
  }
  if (el == 0){
    int row = r0 + r; int best = ri[tid];
    idxp[row] = best;
    dout[OUT_IDX + row] = (float)best;
    atomicAdd(&hist[best], 1.f);
  }
}

// ---------------- quantize ----------------
__global__ __launch_bounds__(256) void quant_kern(const float* __restrict__ zt,
    const int* __restrict__ idxp, const float* __restrict__ embed,
    float* __restrict__ qt, float* __restrict__ redp, float* __restrict__ dout){
  float local = 0.f;
  #pragma unroll
  for (int rr = 0; rr < 4; ++rr){
    int i = blockIdx.x*1024 + rr*256 + threadIdx.x;
    int c = i & 127, p = (i >> 7) & 63, b = i >> 13;
    int e = idxp[b*64 + p];
    float q = embed[(size_t)e*128 + c];
    float d = q - zt[i];
    local += d*d;
    qt[i] = q;
    dout[OUT_QZ + ((size_t)b*128 + c)*64 + p] = q;
  }
  __shared__ float red[256];
  red[threadIdx.x] = local; __syncthreads();
  for (int off = 128; off; off >>= 1){
    if (threadIdx.x < off) red[threadIdx.x] += red[threadIdx.x + off];
    __syncthreads();
  }
  if (threadIdx.x == 0) atomicAdd(redp, red[0]);
}

// ---------------- perplexity + losses ----------------
__global__ __launch_bounds__(256) void perp_kern(const float* __restrict__ hist,
    const float* __restrict__ redp, float* __restrict__ dout){
  __shared__ float red[256];
  float local = 0.f;
  for (int i = threadIdx.x; i < 2048; i += 256){
    float p = hist[i] * (1.f/8192.f);
    local += p * logf(p + 1e-10f);
  }
  red[threadIdx.x] = local; __syncthreads();
  for (int off = 128; off; off >>= 1){
    if (threadIdx.x < off) red[threadIdx.x] += red[threadIdx.x + off];
    __syncthreads();
  }
  if (threadIdx.x == 0){
    float mse = redp[0] * (1.f/1048576.f);
    dout[OUT_LOSS] = 1.2f*mse;
    dout[OUT_CMT]  = mse;
    dout[OUT_PERP] = expf(-red[0]);
  }
}

// ---------------- convT1 ----------------
__global__ __launch_bounds__(256) void convt1_kern(const float* __restrict__ qt,
    const float* __restrict__ wt, const float* __restrict__ cb,
    const float* __restrict__ bns, float* __restrict__ d1){
  int gm = blockIdx.x;
  int b = gm >> 1, op0 = (gm & 1) << 6, oc0 = blockIdx.y << 6;
  int tid = threadIdx.x, tx = tid & 15, ty = tid >> 4;
  __shared__ __align__(16) float As[32*68];
  __shared__ __align__(16) float Bs[32*68];
  float acc[4][4] = {};
  for (int k = 0; k < 4; ++k){
    for (int ic0 = 0; ic0 < 128; ic0 += 32){
      #pragma unroll
      for (int rr = 0; rr < 8; ++rr){
        int e = rr*256 + tid; int m = e >> 5, ic = e & 31;
        int op = op0 + m;
        float v = 0.f;
        if (op >= k && (((op - k) & 1) == 0)){
          int ip = (op - k) >> 1;
          v = qt[((size_t)b*64 + ip)*128 + ic0 + ic];
        }
        As[ic*68 + m] = v;
      }
      #pragma unroll
      for (int rr = 0; rr < 8; ++rr){
        int e = rr*256 + tid; int oc = e & 63, ic = e >> 6;
        Bs[ic*68 + oc] = wt[((size_t)k*128 + ic0 + ic)*512 + oc0 + oc];
      }
      __syncthreads();
      #pragma unroll
      for (int kk = 0; kk < 32; ++kk){
        float4 a4 = *(const float4*)&As[kk*68 + ty*4];
        float4 b4 = *(const float4*)&Bs[kk*68 + tx*4];
        FMA44
      }
      __syncthreads();
    }
  }
  #pragma unroll
  for (int i = 0; i < 4; ++i){
    int op = op0 + ty*4 + i;
    #pragma unroll
    for (int jj = 0; jj < 4; ++jj){
      int oc = oc0 + tx*4 + jj;
      float v = acc[i][jj] + cb[oc];
      v = v*bns[DB1S + oc] + bns[DB1T + oc];
      v = v > 0.f ? v : 0.2f*v;
      d1[((size_t)b*128 + op)*512 + oc] = v;
    }
  }
}

// ---------------- convT2 ----------------
__global__ __launch_bounds__(256) void convt2_kern(const float* __restrict__ d1,
    const float* __restrict__ wt, const float* __restrict__ cb,
    const float* __restrict__ bns, float* __restrict__ dec){
  int gm = blockIdx.x;
  int b = gm >> 2, op0 = (gm & 3) << 6, oc0 = blockIdx.y << 6;
  int tid = threadIdx.x, tx = tid & 15, ty = tid >> 4;
  __shared__ __align__(16) float As[32*68];
  __shared__ __align__(16) float Bs[32*68];
  float acc[4][4] = {};
  for (int k = 0; k < 4; ++k){
    for (int ic0 = 0; ic0 < 512; ic0 += 32){
      #pragma unroll
      for (int rr = 0; rr < 8; ++rr){
        int e = rr*256 + tid; int m = e >> 5, ic = e & 31;
        int op = op0 + m;
        float v = 0.f;
        if (op >= k && (((op - k) & 1) == 0)){
          int ip = (op - k) >> 1;
          v = d1[((size_t)b*128 + ip)*512 + ic0 + ic];
        }
        As[ic*68 + m] = v;
      }
      #pragma unroll
      for (int rr = 0; rr < 8; ++rr){
        int e = rr*256 + tid; int oc = e & 63, ic = e >> 6;
        Bs[ic*68 + oc] = wt[((size_t)k*512 + ic0 + ic)*256 + oc0 + oc];
      }
      __syncthreads();
      #pragma unroll
      for (int kk = 0; kk < 32; ++kk){
        float4 a4 = *(const float4*)&As[kk*68 + ty*4];
        float4 b4 = *(const float4*)&Bs[kk*68 + tx*4];
        FMA44
      }
      __syncthreads();
    }
  }
  #pragma unroll
  for (int i = 0; i < 4; ++i){
    int op = op0 + ty*4 + i;
    #pragma unroll
    for (int jj = 0; jj < 4; ++jj){
      int oc = oc0 + tx*4 + jj;
      float v = acc[i][jj] + cb[oc];
      v = v*bns[DB2S + oc] + bns[DB2T + oc];
      v = v > 0.f ? v : 0.2f*v;
      dec[((size_t)b*256 + op)*256 + oc] = v;
    }
  }
}

// =====================================================================
extern "C" void kernel_launch(void* const* d_in, const int* in_sizes, int n_in,
                              void* d_out, int out_size, void* d_ws, size_t ws_size,
                              hipStream_t stream){
  (void)in_sizes; (void)n_in; (void)out_size; (void)ws_size;
  const float* note  = (const float*)d_in[0];
  const float* skel  = (const float*)d_in[1];
  const float* se    = (const float*)d_in[2];
  const float* ehw   = (const float*)d_in[3];
  const float* ehb   = (const float*)d_in[4];
  const float* ifw   = (const float*)d_in[5];
  const float* ifb   = (const float*)d_in[6];
  const float* gfwih = (const float*)d_in[7];
  const float* gfwhh = (const float*)d_in[8];
  const float* gfbih = (const float*)d_in[9];
  const float* gfbhh = (const float*)d_in[10];
  const float* gbwih = (const float*)d_in[11];
  const float* gbwhh = (const float*)d_in[12];
  const float* gbbih = (const float*)d_in[13];
  const float* gbbhh = (const float*)d_in[14];
  const float* bn0g  = (const float*)d_in[15];
  const float* bn0b  = (const float*)d_in[16];
  const float* bn0m  = (const float*)d_in[17];
  const float* bn0v  = (const float*)d_in[18];
  const float* c1w   = (const float*)d_in[19];
  const float* c1b   = (const float*)d_in[20];
  const float* bn1g  = (const float*)d_in[21];
  const float* bn1b  = (const float*)d_in[22];
  const float* bn1m  = (const float*)d_in[23];
  const float* bn1v  = (const float*)d_in[24];
  const float* c2w   = (const float*)d_in[25];
  const float* c2b   = (const float*)d_in[26];
  const float* bn2g  = (const float*)d_in[27];
  const float* bn2b  = (const float*)d_in[28];
  const float* bn2m  = (const float*)d_in[29];
  const float* bn2v  = (const float*)d_in[30];
  const float* c3w   = (const float*)d_in[31];
  const float* c3b   = (const float*)d_in[32];
  const float* embed = (const float*)d_in[33];
  const float* ct1w  = (const float*)d_in[34];
  const float* ct1b  = (const float*)d_in[35];
  const float* dbn1g = (const float*)d_in[36];
  const float* dbn1b = (const float*)d_in[37];
  const float* dbn1m = (const float*)d_in[38];
  const float* dbn1v = (const float*)d_in[39];
  const float* ct2w  = (const float*)d_in[40];
  const float* ct2b  = (const float*)d_in[41];
  const float* dbn2g = (const float*)d_in[42];
  const float* dbn2b = (const float*)d_in[43];
  const float* dbn2m = (const float*)d_in[44];
  const float* dbn2v = (const float*)d_in[45];
  const float* dhw   = (const float*)d_in[46];
  const float* dhb   = (const float*)d_in[47];
  const float* g1wih = (const float*)d_in[48];
  const float* g1whh = (const float*)d_in[49];
  const float* g1bih = (const float*)d_in[50];
  const float* g1bhh = (const float*)d_in[51];
  const float* g2wih = (const float*)d_in[52];
  const float* g2whh = (const float*)d_in[53];
  const float* g2bih = (const float*)d_in[54];
  const float* g2bhh = (const float*)d_in[55];
  const float* nfw   = (const float*)d_in[56];
  const float* nfb   = (const float*)d_in[57];
  const float* sr    = (const float*)d_in[58];

  float* ws  = (float*)d_ws;
  float* out = (float*)d_out;
  float* ysp  = ws + O_YS;
  float* bnsp = ws + O_BNS;

  // ---- precompute ----
  trans_kern<<<dim3(2048), dim3(256), 0, stream>>>(c1w, c2w, c3w, ct1w, ct2w, ws);
  bn_kern<<<dim3(11), dim3(256), 0, stream>>>(bn0g,bn0b,bn0m,bn0v, bn1g,bn1b,bn1m,bn1v,
                                              bn2g,bn2b,bn2m,bn2v, dbn1g,dbn1b,dbn1m,dbn1v,
                                              dbn2g,dbn2b,dbn2m,dbn2v, bnsp);
  init_kern<<<dim3(512), dim3(256), 0, stream>>>(se, ehw, ehb, dhw, dhb, ws);
  weff_kern<<<dim3(120), dim3(256), 0, stream>>>(gfwih, gfbih, gbwih, gbbih, ifw, ifb, ws);
  esq_kern<<<dim3(8), dim3(256), 0, stream>>>(embed, ws);
  split_w_kern<<<dim3(1024), dim3(256), 0, stream>>>(gfwhh, gbwhh, ws);

  // ---- encoder bi-GRU: ONE persistent cooperative kernel ----
  {
    void* eargs[] = { (void*)&ws, (void*)&note, (void*)&gfbhh, (void*)&gbbhh };
    hipLaunchCooperativeKernel(enc_persist, dim3(256), dim3(256), eargs, 0, stream);
  }

  // ---- conv stack ----
  conv1_kern<<<dim3(256, 8), dim3(256), 0, stream>>>(ysp, ws + O_WT1, c1b, bnsp, ws + O_C1);
  split_w2_kern<<<dim3(2048), dim3(256), 0, stream>>>(g1wih, g1whh, g2wih, g2whh, ws);
  conv2_kern<<<dim3(128, 8), dim3(256), 0, stream>>>(ws + O_C1, ws + O_WT2, c2b, bnsp, ws + O_C2);
  conv3_kern<<<dim3(128, 2), dim3(256), 0, stream>>>(ws + O_C2, ws + O_WT3, c3b, ws + O_ZT);

  // ---- VQ ----
  vq_kern<<<dim3(1024), dim3(256), 0, stream>>>(ws + O_ZT, ws + O_ESQ, embed,
      (int*)(ws + O_IDX), ws + O_HIST, out);
  quant_kern<<<dim3(1024), dim3(256), 0, stream>>>(ws + O_ZT, (const int*)(ws + O_IDX),
      embed, ws + O_QT, ws + O_RED, out);
  perp_kern<<<dim3(1), dim3(256), 0, stream>>>(ws + O_HIST, ws + O_RED, out);

  // ---- decoder convT stack ----
  convt1_kern<<<dim3(256, 8), dim3(256), 0, stream>>>(ws + O_QT, ws + O_WTD1, ct1b, bnsp, ws + O_D1);
  convt2_kern<<<dim3(512, 4), dim3(256), 0, stream>>>(ws + O_D1, ws + O_WTD2, ct2b, bnsp, ws + O_DEC);
  split_dec_kern<<<dim3(2048), dim3(256), 0, stream>>>(ws);

  // ---- autoregressive decoder: ONE persistent cooperative kernel ----
  {
    void* dargs[] = { (void*)&ws, (void*)&skel, (void*)&sr, (void*)&g1wih,
                      (void*)&g1bih, (void*)&g1bhh, (void*)&nfb,
                      (void*)&g2bih, (void*)&g2bhh, (void*)&nfw, (void*)&out };
    hipLaunchCooperativeKernel(dec_persist, dim3(256), dim3(256), dargs, 0, stream);
  }
}

// Round 8
// 14502.843 us; speedup vs baseline: 1.9704x; 1.9704x over previous
//
#include <hip/hip_runtime.h>
#include <math.h>

// =====================================================================
// Note_VQVAE forward, MI355X, round 8: PROVEN r2 multi-launch design
// (kernel boundaries = the only reliable cross-XCD coherence on this
// part; r3-r7 established intra-kernel exchange is not winnable).
// Change vs r2: recurrent kernels widened to 512 threads (8 waves,
// 2 waves/SIMD) via 8-way K split -> halved dependent chains, 2x TLP.
// =====================================================================

#define DI __device__ __forceinline__

// ---------------- workspace layout (float offsets) ----------------
#define O_HF   ((size_t)0)
#define O_HB   ((size_t)131072)
#define O_H1   ((size_t)262144)
#define O_H2   ((size_t)393216)
#define O_WEFF ((size_t)524288)
#define O_BEFF ((size_t)551936)
#define O_BNS  ((size_t)555008)
#define O_ESQ  ((size_t)560640)
#define O_HIST ((size_t)562688)
#define O_RED  ((size_t)564736)
#define O_LOG  ((size_t)564752)     // logits ping-pong 2 x 1152
#define O_IDX  ((size_t)567056)
#define O_ZT   ((size_t)575248)
#define O_QT   ((size_t)1623824)
#define O_C2   ((size_t)2672400)
#define O_C1   ((size_t)6866704)
#define O_WT1  ((size_t)15255312)
#define O_WT2  ((size_t)17352464)
#define O_WT3  ((size_t)18401040)
#define O_WTD1 ((size_t)18466576)
#define O_WTD2 ((size_t)18728720)
#define O_YS   ((size_t)19253008)
#define O_D1   O_YS
#define O_DEC  (O_YS + (size_t)8388608)

#define ESOFF ((size_t)2672400)     // enc weight+h splits; later decs splits
#define DSOFF ((size_t)36030224)    // dec weight+h splits (after O_DEC)

#define BN0S 0
#define BN0T 1024
#define BN1S 2048
#define BN1T 2560
#define BN2S 3072
#define BN2T 3584
#define DB1S 4096
#define DB1T 4608
#define DB2S 5120
#define DB2T 5376

#define OUT_NR   0
#define OUT_QZ   294912
#define OUT_LOSS 1343488
#define OUT_CMT  1343489
#define OUT_IDX  1343490
#define OUT_PERP 1351682

DI float sigm(float x){ return 1.0f/(1.0f + expf(-x)); }

typedef __attribute__((ext_vector_type(8))) short s8v;
typedef __attribute__((ext_vector_type(4))) float f32x4;

DI f32x4 MF(s8v a, s8v b, f32x4 c){
  return __builtin_amdgcn_mfma_f32_16x16x32_bf16(a, b, c, 0, 0, 0);
}
DI s8v LD8(const unsigned short* p){ return *(const s8v*)p; }

// exact 3-way bf16 split of f32 (hi+mid+lo == x exactly), RNE each stage
DI void split3(float x, unsigned short& o0, unsigned short& o1, unsigned short& o2){
  unsigned u0 = __float_as_uint(x);
  unsigned h0 = (u0 + 0x7fffu + ((u0>>16)&1u)) >> 16;
  float x1 = x - __uint_as_float(h0<<16);
  unsigned u1 = __float_as_uint(x1);
  unsigned h1 = (u1 + 0x7fffu + ((u1>>16)&1u)) >> 16;
  float x2 = x1 - __uint_as_float(h1<<16);
  unsigned u2 = __float_as_uint(x2);
  unsigned h2 = (u2 + 0x7fffu + ((u2>>16)&1u)) >> 16;
  o0 = (unsigned short)h0; o1 = (unsigned short)h1; o2 = (unsigned short)h2;
}

#define MF8(A0,A1,A2,Q0,Q1,Q2,C0,C1) \
  C0 = MF(A0,Q0,C0); C1 = MF(A0,Q1,C1); \
  C0 = MF(A1,Q1,C0); C1 = MF(A1,Q0,C1); \
  C0 = MF(A0,Q2,C0); C1 = MF(A2,Q0,C1); \
  C0 = MF(A2,Q1,C0); C1 = MF(A1,Q2,C1);

#define FMA44 \
  acc[0][0] += a4.x*b4.x; acc[0][1] += a4.x*b4.y; acc[0][2] += a4.x*b4.z; acc[0][3] += a4.x*b4.w; \
  acc[1][0] += a4.y*b4.x; acc[1][1] += a4.y*b4.y; acc[1][2] += a4.y*b4.z; acc[1][3] += a4.y*b4.w; \
  acc[2][0] += a4.z*b4.x; acc[2][1] += a4.z*b4.y; acc[2][2] += a4.z*b4.z; acc[2][3] += a4.z*b4.w; \
  acc[3][0] += a4.w*b4.x; acc[3][1] += a4.w*b4.y; acc[3][2] += a4.w*b4.z; acc[3][3] += a4.w*b4.w;

// ---------------- weight transposes into ws (convs) ----------------
__global__ void trans_kern(const float* __restrict__ c1w, const float* __restrict__ c2w,
                           const float* __restrict__ c3w, const float* __restrict__ ct1w,
                           const float* __restrict__ ct2w, float* __restrict__ ws){
  const int A1 = 2097152, A2 = 3145728, A3 = 3211264, A4 = 3473408, A5 = 3997696;
  for (int i = blockIdx.x*256 + threadIdx.x; i < A5; i += gridDim.x*256){
    if (i < A1){
      int j = i; int oc = j & 511; int t = j >> 9; int ic = t & 1023; int k = t >> 10;
      ws[O_WT1 + j] = c1w[((size_t)oc*1024 + ic)*4 + k];
    } else if (i < A2){
      int j = i - A1; int oc = j & 511; int t = j >> 9; int ic = t & 511; int k = t >> 9;
      ws[O_WT2 + j] = c2w[((size_t)oc*512 + ic)*4 + k];
    } else if (i < A3){
      int j = i - A2; int oc = j & 127; int ic = j >> 7;
      ws[O_WT3 + j] = c3w[(size_t)oc*512 + ic];
    } else if (i < A4){
      int j = i - A3; int oc = j & 511; int t = j >> 9; int ic = t & 127; int k = t >> 7;
      ws[O_WTD1 + j] = ct1w[((size_t)ic*512 + oc)*4 + k];
    } else {
      int j = i - A4; int oc = j & 255; int t = j >> 8; int ic = t & 511; int k = t >> 9;
      ws[O_WTD2 + j] = ct2w[((size_t)ic*256 + oc)*4 + k];
    }
  }
}

// ---------------- BN scale/shift precompute ----------------
__global__ void bn_kern(const float* g0,const float* b0,const float* m0,const float* v0,
                        const float* g1,const float* b1,const float* m1,const float* v1,
                        const float* g2,const float* b2,const float* m2,const float* v2,
                        const float* gd1,const float* bd1,const float* md1,const float* vd1,
                        const float* gd2,const float* bd2,const float* md2,const float* vd2,
                        float* __restrict__ bns){
  int i = blockIdx.x*256 + threadIdx.x;
  if (i >= 2816) return;
  const float *g,*b,*m,*v; int c, so, to;
  if (i < 1024){ g=g0;b=b0;m=m0;v=v0;c=i;so=BN0S;to=BN0T; }
  else if (i < 1536){ g=g1;b=b1;m=m1;v=v1;c=i-1024;so=BN1S;to=BN1T; }
  else if (i < 2048){ g=g2;b=b2;m=m2;v=v2;c=i-1536;so=BN2S;to=BN2T; }
  else if (i < 2560){ g=gd1;b=bd1;m=md1;v=vd1;c=i-2048;so=DB1S;to=DB1T; }
  else              { g=gd2;b=bd2;m=md2;v=vd2;c=i-2560;so=DB2S;to=DB2T; }
  float s = g[c]*rsqrtf(v[c] + 1e-5f);
  bns[so + c] = s;
  bns[to + c] = b[c] - m[c]*s;
}

// ---------------- hid / decoder-h1 init + enc h splits ----------------
__global__ __launch_bounds__(256) void init_kern(const float* __restrict__ se,
    const float* __restrict__ ehw, const float* __restrict__ ehb,
    const float* __restrict__ dhw, const float* __restrict__ dhb, float* __restrict__ ws){
  int idx = blockIdx.x*256 + threadIdx.x;
  int n = idx & 1023, b = idx >> 10;
  const float* w; float bias;
  if (n < 512){ w = ehw + (size_t)n*256; bias = ehb[n]; }
  else        { w = dhw + (size_t)(n-512)*256; bias = dhb[n-512]; }
  const float* sp = se + (size_t)b*256;
  float acc = bias;
  for (int k = 0; k < 256; ++k) acc += sp[k]*w[k];
  if (n < 512){
    ws[O_HF + 65536 + b*512 + n] = acc;
    ws[O_HB + 65536 + b*512 + n] = acc;
    unsigned short s0,s1,s2; split3(acc, s0,s1,s2);
    unsigned short* esh = (unsigned short*)(ws + ESOFF) + 4718592;
    int off = 196608 + b*512 + n;            // buf1
    esh[off] = s0; esh[off+65536] = s1; esh[off+131072] = s2;          // fwd
    esh[393216+off] = s0; esh[393216+off+65536] = s1; esh[393216+off+131072] = s2; // bwd
  } else {
    ws[O_H1 + 65536 + b*512 + (n-512)] = acc;
  }
}

// ---------------- Weff = wih @ ifw,  beff = wih @ ifb + bih ----------------
__global__ __launch_bounds__(256) void weff_kern(const float* __restrict__ gfwih,
    const float* __restrict__ gfbih, const float* __restrict__ gbwih, const float* __restrict__ gbbih,
    const float* __restrict__ ifw, const float* __restrict__ ifb, float* __restrict__ ws){
  int idx = blockIdx.x*256 + threadIdx.x;
  if (idx >= 30720) return;
  int dir = idx / 15360; int r = idx - dir*15360;
  int j3 = r / 10; int d = r - j3*10;
  const float* wih = dir ? gbwih : gfwih;
  float acc = 0.f;
  if (d < 9){
    for (int k = 0; k < 512; ++k) acc += wih[(size_t)j3*512 + k]*ifw[k*9 + d];
    ws[O_WEFF + dir*13824 + j3*9 + d] = acc;
  } else {
    for (int k = 0; k < 512; ++k) acc += wih[(size_t)j3*512 + k]*ifb[k];
    acc += (dir ? gbbih : gfbih)[j3];
    ws[O_BEFF + dir*1536 + j3] = acc;
  }
}

// ---------------- |embed|^2 + zero hist/red ----------------
__global__ __launch_bounds__(256) void esq_kern(const float* __restrict__ embed, float* __restrict__ ws){
  int e = blockIdx.x*256 + threadIdx.x;
  float acc = 0.f;
  for (int c = 0; c < 128; ++c){ float t = embed[(size_t)e*128 + c]; acc += t*t; }
  ws[O_ESQ + e] = acc;
  if (blockIdx.x == 0){
    for (int i = threadIdx.x; i < 2048; i += 256) ws[O_HIST + i] = 0.f;
    if (threadIdx.x < 16) ws[O_RED + threadIdx.x] = 0.f;
  }
}

// ---------------- encoder recurrent weight splits ----------------
__global__ void split_w_kern(const float* __restrict__ gfwhh,
    const float* __restrict__ gbwhh, float* __restrict__ ws){
  unsigned short* es = (unsigned short*)(ws + ESOFF);
  for (int i = blockIdx.x*256 + threadIdx.x; i < 1572864; i += gridDim.x*256){
    int half = i >= 786432;
    int idx = i - (half ? 786432 : 0);
    float x = half ? gbwhh[idx] : gfwhh[idx];
    unsigned short s0,s1,s2; split3(x,s0,s1,s2);
    unsigned short* d = es + (half ? 2359296 : 0);
    d[idx] = s0; d[idx+786432] = s1; d[idx+1572864] = s2;
  }
}

// ---------------- decoder weight splits + h1-init splits (after conv1) ----
__global__ void split_w2_kern(const float* __restrict__ g1wih, const float* __restrict__ g1whh,
    const float* __restrict__ g2wih, const float* __restrict__ g2whh, float* __restrict__ ws){
  unsigned short* dsb = (unsigned short*)(ws + DSOFF);
  const int total = 393216 + 3*786432 + 65536;  // 2818048
  for (int i = blockIdx.x*256 + threadIdx.x; i < total; i += gridDim.x*256){
    float x; unsigned short* d; int off, stride;
    if (i < 393216){
      int row = i>>8, k = i&255;
      x = g1wih[(size_t)row*274 + 9 + k]; d = dsb; off = i; stride = 393216;
    } else if (i < 1179648){
      int idx = i-393216; x = g1whh[idx]; d = dsb + 1179648; off = idx; stride = 786432;
    } else if (i < 1966080){
      int idx = i-1179648; x = g2wih[idx]; d = dsb + 3538944; off = idx; stride = 786432;
    } else if (i < 2752512){
      int idx = i-1966080; x = g2whh[idx]; d = dsb + 5898240; off = idx; stride = 786432;
    } else {
      int idx = i-2752512; x = ws[O_H1 + 65536 + idx];
      d = dsb + 8257536 + 196608; off = idx; stride = 65536;   // h1 buf1 splits
    }
    unsigned short s0,s1,s2; split3(x,s0,s1,s2);
    d[off] = s0; d[off+stride] = s1; d[off+2*stride] = s2;
  }
}

// ---------------- dec-input (convT2 output) splits ----------------
__global__ void split_dec_kern(float* __restrict__ ws){
  unsigned short* decs = (unsigned short*)(ws + ESOFF);
  const float* dec = ws + O_DEC;
  for (int i = blockIdx.x*256 + threadIdx.x; i < 8388608; i += gridDim.x*256){
    unsigned short s0,s1,s2; split3(dec[i],s0,s1,s2);
    decs[i] = s0; decs[i+8388608] = s1; decs[i+16777216] = s2;
  }
}

// ---------------- encoder GRU step, MFMA, 512 threads ----------------
// grid 256: dir=bi>>7, bt=(bi>>5)&3 (32 b), jt=bi&31 (16 j).
// 8 waves: m=w&1 (16-b half), kq=w>>1 (K quarter: 4 Ktiles of 32).
__global__ __launch_bounds__(512) void enc_step_mfma(
    float* __restrict__ ws, const float* __restrict__ note,
    const float* __restrict__ gfbhh, const float* __restrict__ gbbhh, int step){
  int bi = blockIdx.x;
  int dir = bi>>7, bt = (bi>>5)&3, jt = bi&31;
  int b0 = bt*32, j0 = jt*16;
  int tid = threadIdx.x, w = tid>>6, l = tid&63;
  int m = w&1, kq = w>>1;
  int pb = (step+1)&1, cb = step&1;
  float* hprev = ws + (dir? O_HB : O_HF) + (size_t)pb*65536;
  float* hnext = ws + (dir? O_HB : O_HF) + (size_t)cb*65536;
  unsigned short* esh = (unsigned short*)(ws + ESOFF) + 4718592 + dir*393216;
  const unsigned short* hsp = esh + pb*196608;
  unsigned short* hsn = esh + cb*196608;
  const unsigned short* wsp = (const unsigned short*)(ws + ESOFF) + dir*2359296;
  const float* weff = ws + O_WEFF + dir*13824;
  const float* beff = ws + O_BEFF + dir*1536;
  const float* bhh = dir? gbbhh : gfbhh;
  const float* bns = ws + O_BNS;
  float* ys = ws + O_YS;

  const unsigned short* ab = hsp + (size_t)(b0 + m*16 + (l&15))*512 + kq*128 + ((l>>4)<<3);
  const unsigned short* bb = wsp + (size_t)(j0 + (l&15))*512 + kq*128 + ((l>>4)<<3);
  f32x4 z4 = {0.f,0.f,0.f,0.f};
  f32x4 acc[3][2] = {{z4,z4},{z4,z4},{z4,z4}};
  #pragma unroll
  for (int kt = 0; kt < 4; ++kt){
    s8v a0 = LD8(ab + kt*32);
    s8v a1 = LD8(ab + 65536 + kt*32);
    s8v a2 = LD8(ab + 131072 + kt*32);
    #pragma unroll
    for (int g = 0; g < 3; ++g){
      const unsigned short* bp = bb + g*262144 + kt*32;
      s8v q0 = LD8(bp);
      s8v q1 = LD8(bp + 786432);
      s8v q2 = LD8(bp + 1572864);
      MF8(a0,a1,a2, q0,q1,q2, acc[g][0], acc[g][1])
    }
  }
  __shared__ float red[6144];
  #pragma unroll
  for (int g = 0; g < 3; ++g){
    f32x4 s = acc[g][0] + acc[g][1];
    #pragma unroll
    for (int i = 0; i < 4; ++i) red[((w*3+g)<<8) + (i<<6) + l] = s[i];
  }
  __syncthreads();
  // epilogue: exactly one (b,j) output per thread
  int t = dir ? 255-step : step;
  int i = kq;
  int b = b0 + m*16 + ((l>>4)<<2) + i;
  int j = j0 + (l&15);
  float Y[3];
  #pragma unroll
  for (int g = 0; g < 3; ++g){
    float y = 0.f;
    #pragma unroll
    for (int q = 0; q < 4; ++q)
      y += red[(((m + 2*q)*3 + g)<<8) + (i<<6) + l];
    Y[g] = y;
  }
  const float* nt = note + ((size_t)b*256 + t)*9;
  float gi[3];
  #pragma unroll
  for (int g = 0; g < 3; ++g){
    const float* wr = weff + (size_t)(g*512+j)*9;
    float a = beff[g*512+j];
    #pragma unroll
    for (int d = 0; d < 9; ++d) a += nt[d]*wr[d];
    gi[g] = a;
  }
  float hpv = hprev[(size_t)b*512 + j];
  float r = sigm(gi[0] + Y[0] + bhh[j]);
  float zz = sigm(gi[1] + Y[1] + bhh[512+j]);
  float nn = tanhf(gi[2] + r*(Y[2] + bhh[1024+j]));
  float h = (1.f - zz)*nn + zz*hpv;
  hnext[(size_t)b*512 + j] = h;
  unsigned short s0,s1,s2; split3(h, s0,s1,s2);
  int off = b*512 + j;
  hsn[off] = s0; hsn[off+65536] = s1; hsn[off+131072] = s2;
  int c = dir*512 + j;
  ys[((size_t)b*256 + t)*1024 + c] = h*bns[BN0S + c] + bns[BN0T + c];
}

// ---------------- decoder GRU1 step, MFMA, 512 threads ----------------
// grid 256: bt=bi>>5 (16 b), jt=bi&31 (16 j). 8 waves = 8-way K split.
__global__ __launch_bounds__(512) void dec_k1_mfma(
    float* __restrict__ ws, const float* __restrict__ skel, const float* __restrict__ sr,
    const float* __restrict__ w1ih, const float* __restrict__ b1ih,
    const float* __restrict__ b1hh, const float* __restrict__ nfb,
    float* __restrict__ dout, int step){
  int bi = blockIdx.x;
  int bt = bi>>5, jt = bi&31;
  int b0 = bt*16, j0 = jt*16;
  int tid = threadIdx.x, w = tid>>6, l = tid&63;
  int pb = (step+1)&1, cb = step&1;
  const float* h1p = ws + O_H1 + (size_t)pb*65536;
  float* h1n = ws + O_H1 + (size_t)cb*65536;
  const float* logp = ws + O_LOG + (size_t)pb*1152;
  float* logc = ws + O_LOG + (size_t)cb*1152;
  unsigned short* dsb = (unsigned short*)(ws + DSOFF);
  const unsigned short* h1sp = dsb + 8257536 + pb*196608;
  unsigned short* h1sn = dsb + 8257536 + cb*196608;
  const unsigned short* decs = (const unsigned short*)(ws + ESOFF);
  const unsigned short* w1d = dsb;
  const unsigned short* w1h = dsb + 1179648;

  __shared__ float fbs[144], ssh[144];
  __shared__ float red[12288];
  if (tid < 144){
    int bb = tid/9, d = tid - bb*9; int b = b0 + bb;
    float fv = 0.f;
    if (step > 0){
      float lg = logp[b*9 + d];
      fv = (sigm(lg) - sr[(size_t)(step-1)*1152 + b*9 + d]) > 0.f ? 1.f : 0.f;
    }
    fbs[tid] = fv;
    ssh[tid] = skel[((size_t)b*256 + step)*9 + d];
  }
  if (bi == 0){
    for (int idx = tid; idx < 1152; idx += 512){
      logc[idx] = nfb[idx % 9];
      if (step > 0) dout[OUT_NR + (size_t)(idx/9)*2304 + (step-1)*9 + (idx%9)] = logp[idx];
    }
  }
  f32x4 z4 = {0.f,0.f,0.f,0.f};
  f32x4 gia[3][2] = {{z4,z4},{z4,z4},{z4,z4}};
  f32x4 gha[3][2] = {{z4,z4},{z4,z4},{z4,z4}};
  // x-part: K=256 over dec splits, 1 Ktile per wave
  {
    const unsigned short* ab = decs + (size_t)(b0 + (l&15))*65536 + step*256 + w*32 + ((l>>4)<<3);
    const unsigned short* bbp = w1d + (size_t)(j0 + (l&15))*256 + w*32 + ((l>>4)<<3);
    s8v a0 = LD8(ab);
    s8v a1 = LD8(ab + 8388608);
    s8v a2 = LD8(ab + 16777216);
    #pragma unroll
    for (int g = 0; g < 3; ++g){
      const unsigned short* bp = bbp + g*131072;
      s8v q0 = LD8(bp);
      s8v q1 = LD8(bp + 393216);
      s8v q2 = LD8(bp + 786432);
      MF8(a0,a1,a2, q0,q1,q2, gia[g][0], gia[g][1])
    }
  }
  // h-part: K=512 over h1 splits, 2 Ktiles per wave
  {
    const unsigned short* ab = h1sp + (size_t)(b0 + (l&15))*512 + w*64 + ((l>>4)<<3);
    const unsigned short* bbp = w1h + (size_t)(j0 + (l&15))*512 + w*64 + ((l>>4)<<3);
    #pragma unroll
    for (int kt = 0; kt < 2; ++kt){
      s8v a0 = LD8(ab + kt*32);
      s8v a1 = LD8(ab + 65536 + kt*32);
      s8v a2 = LD8(ab + 131072 + kt*32);
      #pragma unroll
      for (int g = 0; g < 3; ++g){
        const unsigned short* bp = bbp + g*262144 + kt*32;
        s8v q0 = LD8(bp);
        s8v q1 = LD8(bp + 786432);
        s8v q2 = LD8(bp + 1572864);
        MF8(a0,a1,a2, q0,q1,q2, gha[g][0], gha[g][1])
      }
    }
  }
  #pragma unroll
  for (int g = 0; g < 3; ++g){
    f32x4 s = gia[g][0] + gia[g][1];
    f32x4 t = gha[g][0] + gha[g][1];
    #pragma unroll
    for (int i = 0; i < 4; ++i){
      red[((w*6+g)<<8) + (i<<6) + l] = s[i];
      red[((w*6+g+3)<<8) + (i<<6) + l] = t[i];
    }
  }
  __syncthreads();
  if (w < 4){
    int i = w;
    int b = b0 + ((l>>4)<<2) + i;
    int j = j0 + (l&15);
    float GI[3], GH[3];
    #pragma unroll
    for (int pg = 0; pg < 3; ++pg){
      float a = 0.f, c = 0.f;
      #pragma unroll
      for (int ww = 0; ww < 8; ++ww){
        a += red[((ww*6+pg)<<8)+(i<<6)+l];
        c += red[((ww*6+pg+3)<<8)+(i<<6)+l];
      }
      GI[pg] = a; GH[pg] = c;
    }
    int bb = b - b0;
    #pragma unroll
    for (int g = 0; g < 3; ++g){
      const float* wr = w1ih + (size_t)(g*512+j)*274;
      float a = GI[g] + b1ih[g*512+j];
      #pragma unroll
      for (int d = 0; d < 9; ++d) a += fbs[bb*9+d]*wr[d] + ssh[bb*9+d]*wr[265+d];
      GI[g] = a;
    }
    float hpv = h1p[(size_t)b*512 + j];
    float r = sigm(GI[0] + GH[0] + b1hh[j]);
    float zz = sigm(GI[1] + GH[1] + b1hh[512+j]);
    float nn = tanhf(GI[2] + r*(GH[2] + b1hh[1024+j]));
    float h = (1.f-zz)*nn + zz*hpv;
    h1n[(size_t)b*512 + j] = h;
    unsigned short s0,s1,s2; split3(h,s0,s1,s2);
    int off = b*512 + j;
    h1sn[off] = s0; h1sn[off+65536] = s1; h1sn[off+131072] = s2;
  }
}

// ---------------- decoder GRU2 step + logits, MFMA, 512 threads ----------------
__global__ __launch_bounds__(512) void dec_k2_mfma(
    float* __restrict__ ws, const float* __restrict__ b2ih, const float* __restrict__ b2hh,
    const float* __restrict__ nfw, int step){
  int bi = blockIdx.x;
  int bt = bi>>5, jt = bi&31;
  int b0 = bt*16, j0 = jt*16;
  int tid = threadIdx.x, w = tid>>6, l = tid&63;
  int pb = (step+1)&1, cb = step&1;
  const float* h1n = ws + O_H1 + (size_t)cb*65536;
  const float* h2p = (step==0) ? h1n : ws + O_H2 + (size_t)pb*65536;
  float* h2n = ws + O_H2 + (size_t)cb*65536;
  float* logc = ws + O_LOG + (size_t)cb*1152;
  unsigned short* dsb = (unsigned short*)(ws + DSOFF);
  const unsigned short* h1sn = dsb + 8257536 + cb*196608;
  const unsigned short* h2sp = (step==0) ? h1sn : dsb + 8650752 + pb*196608;
  unsigned short* h2sn = dsb + 8650752 + cb*196608;
  const unsigned short* w2i = dsb + 3538944;
  const unsigned short* w2h = dsb + 5898240;

  __shared__ float red[12288];
  __shared__ float hsm[256];
  f32x4 z4 = {0.f,0.f,0.f,0.f};
  f32x4 gia[3][2] = {{z4,z4},{z4,z4},{z4,z4}};
  f32x4 gha[3][2] = {{z4,z4},{z4,z4},{z4,z4}};
  // x-part: A = new h1 splits, 2 Ktiles per wave
  {
    const unsigned short* ab = h1sn + (size_t)(b0 + (l&15))*512 + w*64 + ((l>>4)<<3);
    const unsigned short* bbp = w2i + (size_t)(j0 + (l&15))*512 + w*64 + ((l>>4)<<3);
    #pragma unroll
    for (int kt = 0; kt < 2; ++kt){
      s8v a0 = LD8(ab + kt*32);
      s8v a1 = LD8(ab + 65536 + kt*32);
      s8v a2 = LD8(ab + 131072 + kt*32);
      #pragma unroll
      for (int g = 0; g < 3; ++g){
        const unsigned short* bp = bbp + g*262144 + kt*32;
        s8v q0 = LD8(bp);
        s8v q1 = LD8(bp + 786432);
        s8v q2 = LD8(bp + 1572864);
        MF8(a0,a1,a2, q0,q1,q2, gia[g][0], gia[g][1])
      }
    }
  }
  // h-part: A = prev h2 splits (h1 splits at step 0), 2 Ktiles per wave
  {
    const unsigned short* ab = h2sp + (size_t)(b0 + (l&15))*512 + w*64 + ((l>>4)<<3);
    const unsigned short* bbp = w2h + (size_t)(j0 + (l&15))*512 + w*64 + ((l>>4)<<3);
    #pragma unroll
    for (int kt = 0; kt < 2; ++kt){
      s8v a0 = LD8(ab + kt*32);
      s8v a1 = LD8(ab + 65536 + kt*32);
      s8v a2 = LD8(ab + 131072 + kt*32);
      #pragma unroll
      for (int g = 0; g < 3; ++g){
        const unsigned short* bp = bbp + g*262144 + kt*32;
        s8v q0 = LD8(bp);
        s8v q1 = LD8(bp + 786432);
        s8v q2 = LD8(bp + 1572864);
        MF8(a0,a1,a2, q0,q1,q2, gha[g][0], gha[g][1])
      }
    }
  }
  #pragma unroll
  for (int g = 0; g < 3; ++g){
    f32x4 s = gia[g][0] + gia[g][1];
    f32x4 t = gha[g][0] + gha[g][1];
    #pragma unroll
    for (int i = 0; i < 4; ++i){
      red[((w*6+g)<<8) + (i<<6) + l] = s[i];
      red[((w*6+g+3)<<8) + (i<<6) + l] = t[i];
    }
  }
  __syncthreads();
  if (w < 4){
    int i = w;
    int b = b0 + ((l>>4)<<2) + i;
    int j = j0 + (l&15);
    float GI[3], GH[3];
    #pragma unroll
    for (int pg = 0; pg < 3; ++pg){
      float a = 0.f, c = 0.f;
      #pragma unroll
      for (int ww = 0; ww < 8; ++ww){
        a += red[((ww*6+pg)<<8)+(i<<6)+l];
        c += red[((ww*6+pg+3)<<8)+(i<<6)+l];
      }
      GI[pg] = a; GH[pg] = c;
    }
    float hpv = h2p[(size_t)b*512 + j];
    float r = sigm(GI[0] + b2ih[j] + GH[0] + b2hh[j]);
    float zz = sigm(GI[1] + b2ih[512+j] + GH[1] + b2hh[512+j]);
    float nn = tanhf(GI[2] + b2ih[1024+j] + r*(GH[2] + b2hh[1024+j]));
    float h = (1.f-zz)*nn + zz*hpv;
    h2n[(size_t)b*512 + j] = h;
    unsigned short s0,s1,s2; split3(h,s0,s1,s2);
    int off = b*512 + j;
    h2sn[off] = s0; h2sn[off+65536] = s1; h2sn[off+131072] = s2;
    hsm[(b-b0)*16 + (j-j0)] = h;
  }
  __syncthreads();
  if (tid < 144){
    int bq = tid/9, d = tid - bq*9;
    float v = 0.f;
    #pragma unroll
    for (int jl = 0; jl < 16; ++jl) v += hsm[bq*16+jl]*nfw[(size_t)d*512 + j0 + jl];
    atomicAdd(&logc[(b0+bq)*9 + d], v);
  }
}

// ---------------- conv1 ----------------
__global__ __launch_bounds__(256) void conv1_kern(const float* __restrict__ ysb,
    const float* __restrict__ wt, const float* __restrict__ cb,
    const float* __restrict__ bns, float* __restrict__ outp){
  int gm = blockIdx.x, gn = blockIdx.y;
  int b = gm >> 1, ot0 = (gm & 1) << 6, oc0 = gn << 6;
  int tid = threadIdx.x, tx = tid & 15, ty = tid >> 4;
  __shared__ __align__(16) float As[32*68];
  __shared__ __align__(16) float Bs[32*68];
  float acc[4][4] = {};
  for (int k = 0; k < 4; ++k){
    for (int ic0 = 0; ic0 < 1024; ic0 += 32){
      #pragma unroll
      for (int rr = 0; rr < 8; ++rr){
        int e = rr*256 + tid; int m = e >> 5, ic = e & 31;
        int tin = ((ot0 + m) << 1) + k - 1;
        float v = 0.f;
        if ((unsigned)tin < 256u) v = ysb[((size_t)b*256 + tin)*1024 + ic0 + ic];
        As[ic*68 + m] = v;
      }
      #pragma unroll
      for (int rr = 0; rr < 8; ++rr){
        int e = rr*256 + tid; int oc = e & 63, ic = e >> 6;
        Bs[ic*68 + oc] = wt[((size_t)k*1024 + ic0 + ic)*512 + oc0 + oc];
      }
      __syncthreads();
      #pragma unroll
      for (int kk = 0; kk < 32; ++kk){
        float4 a4 = *(const float4*)&As[kk*68 + ty*4];
        float4 b4 = *(const float4*)&Bs[kk*68 + tx*4];
        FMA44
      }
      __syncthreads();
    }
  }
  #pragma unroll
  for (int i = 0; i < 4; ++i){
    int ot = ot0 + ty*4 + i;
    #pragma unroll
    for (int jj = 0; jj < 4; ++jj){
      int oc = oc0 + tx*4 + jj;
      float v = acc[i][jj] + cb[oc];
      v = v*bns[BN1S + oc] + bns[BN1T + oc];
      v = v > 0.f ? v : 0.2f*v;
      outp[((size_t)b*128 + ot)*512 + oc] = v;
    }
  }
}

// ---------------- conv2 ----------------
__global__ __launch_bounds__(256) void conv2_kern(const float* __restrict__ c1o,
    const float* __restrict__ wt, const float* __restrict__ cb,
    const float* __restrict__ bns, float* __restrict__ outp){
  int b = blockIdx.x, oc0 = blockIdx.y << 6;
  int tid = threadIdx.x, tx = tid & 15, ty = tid >> 4;
  __shared__ __align__(16) float As[32*68];
  __shared__ __align__(16) float Bs[32*68];
  float acc[4][4] = {};
  for (int k = 0; k < 4; ++k){
    for (int ic0 = 0; ic0 < 512; ic0 += 32){
      #pragma unroll
      for (int rr = 0; rr < 8; ++rr){
        int e = rr*256 + tid; int m = e >> 5, ic = e & 31;
        int tin = (m << 1) + k - 1;
        float v = 0.f;
        if ((unsigned)tin < 128u) v = c1o[((size_t)b*128 + tin)*512 + ic0 + ic];
        As[ic*68 + m] = v;
      }
      #pragma unroll
      for (int rr = 0; rr < 8; ++rr){
        int e = rr*256 + tid; int oc = e & 63, ic = e >> 6;
        Bs[ic*68 + oc] = wt[((size_t)k*512 + ic0 + ic)*512 + oc0 + oc];
      }
      __syncthreads();
      #pragma unroll
      for (int kk = 0; kk < 32; ++kk){
        float4 a4 = *(const float4*)&As[kk*68 + ty*4];
        float4 b4 = *(const float4*)&Bs[kk*68 + tx*4];
        FMA44
      }
      __syncthreads();
    }
  }
  #pragma unroll
  for (int i = 0; i < 4; ++i){
    int ot = ty*4 + i;
    #pragma unroll
    for (int jj = 0; jj < 4; ++jj){
      int oc = oc0 + tx*4 + jj;
      float v = acc[i][jj] + cb[oc];
      v = v*bns[BN2S + oc] + bns[BN2T + oc];
      v = v > 0.f ? v : 0.2f*v;
      outp[((size_t)b*64 + ot)*512 + oc] = v;
    }
  }
}

// ---------------- conv3 ----------------
__global__ __launch_bounds__(256) void conv3_kern(const float* __restrict__ c2o,
    const float* __restrict__ wt, const float* __restrict__ cb, float* __restrict__ zt){
  int row0 = blockIdx.x << 6, oc0 = blockIdx.y << 6;
  int tid = threadIdx.x, tx = tid & 15, ty = tid >> 4;
  __shared__ __align__(16) float As[32*68];
  __shared__ __align__(16) float Bs[32*68];
  float acc[4][4] = {};
  for (int ic0 = 0; ic0 < 512; ic0 += 32){
    #pragma unroll
    for (int rr = 0; rr < 8; ++rr){
      int e = rr*256 + tid; int m = e >> 5, ic = e & 31;
      As[ic*68 + m] = c2o[((size_t)(row0 + m))*512 + ic0 + ic];
    }
    #pragma unroll
    for (int rr = 0; rr < 8; ++rr){
      int e = rr*256 + tid; int oc = e & 63, ic = e >> 6;
      Bs[ic*68 + oc] = wt[(size_t)(ic0 + ic)*128 + oc0 + oc];
    }
    __syncthreads();
    #pragma unroll
    for (int kk = 0; kk < 32; ++kk){
      float4 a4 = *(const float4*)&As[kk*68 + ty*4];
      float4 b4 = *(const float4*)&Bs[kk*68 + tx*4];
      FMA44
    }
    __syncthreads();
  }
  #pragma unroll
  for (int i = 0; i < 4; ++i){
    int row = row0 + ty*4 + i;
    #pragma unroll
    for (int jj = 0; jj < 4; ++jj){
      int oc = oc0 + tx*4 + jj;
      zt[(size_t)row*128 + oc] = acc[i][jj] + cb[oc];
    }
  }
}

// ---------------- VQ argmin ----------------
__global__ __launch_bounds__(256) void vq_kern(const float* __restrict__ zt,
    const float* __restrict__ esq, const float* __restrict__ embed,
    int* __restrict__ idxp, float* __restrict__ hist, float* __restrict__ dout){
  int r0 = blockIdx.x * 8;
  int tid = threadIdx.x;
  int r = tid >> 5, el = tid & 31;
  __shared__ __align__(16) float zsh[1024];
  __shared__ __align__(16) float esh[4096];
  __shared__ float rv[256]; __shared__ int ri[256];
  for (int idx = tid; idx < 1024; idx += 256) zsh[idx] = zt[(size_t)r0*128 + idx];
  float minv = 3.4e38f; int mini = 0;
  for (int e0 = 0; e0 < 2048; e0 += 32){
    for (int idx = tid; idx < 4096; idx += 256){
      int ee = idx >> 7, c = idx & 127;
      esh[ee*128 + ((((c >> 2) ^ (ee & 31)) & 31) << 2) + (c & 3)] = embed[(size_t)(e0 + ee)*128 + c];
    }
    __syncthreads();
    float dot = 0.f;
    #pragma unroll
    for (int c0 = 0; c0 < 128; c0 += 4){
      float4 zq = *(const float4*)&zsh[r*128 + c0];
      float4 e4 = *(const float4*)&esh[el*128 + ((((c0 >> 2) ^ (el & 31)) & 31) << 2)];
      dot += zq.x*e4.x + zq.y*e4.y + zq.z*e4.z + zq.w*e4.w;
    }
    float d = esq[e0 + el] - 2.f*dot;
    if (d < minv){ minv = d; mini = e0 + el; }
    __syncthreads();
  }
  rv[tid] = minv; ri[tid] = mini;
  __syncthreads();
  for (int off = 16; off > 0; off >>= 1){
    if (el < off){
      float ov = rv[tid + off]; int oi = ri[tid + off];
      if (ov < rv[tid] || (ov == rv[tid] && oi < ri[tid])){ rv[tid] = ov; ri[tid] = oi; }
    }
    __syncthreads();
  }
  if (el == 0){
    int row = r0 + r; int best = ri[tid];
    idxp[row] = best;
    dout[OUT_IDX + row] = (float)best;
    atomicAdd(&hist[best], 1.f);
  }
}

// ---------------- quantize ----------------
__global__ __launch_bounds__(256) void quant_kern(const float* __restrict__ zt,
    const int* __restrict__ idxp, const float* __restrict__ embed,
    float* __restrict__ qt, float* __restrict__ redp, float* __restrict__ dout){
  float local = 0.f;
  #pragma unroll
  for (int rr = 0; rr < 4; ++rr){
    int i = blockIdx.x*1024 + rr*256 + threadIdx.x;
    int c = i & 127, p = (i >> 7) & 63, b = i >> 13;
    int e = idxp[b*64 + p];
    float q = embed[(size_t)e*128 + c];
    float d = q - zt[i];
    local += d*d;
    qt[i] = q;
    dout[OUT_QZ + ((size_t)b*128 + c)*64 + p] = q;
  }
  __shared__ float red[256];
  red[threadIdx.x] = local; __syncthreads();
  for (int off = 128; off; off >>= 1){
    if (threadIdx.x < off) red[threadIdx.x] += red[threadIdx.x + off];
    __syncthreads();
  }
  if (threadIdx.x == 0) atomicAdd(redp, red[0]);
}

// ---------------- perplexity + losses ----------------
__global__ __launch_bounds__(256) void perp_kern(const float* __restrict__ hist,
    const float* __restrict__ redp, float* __restrict__ dout){
  __shared__ float red[256];
  float local = 0.f;
  for (int i = threadIdx.x; i < 2048; i += 256){
    float p = hist[i] * (1.f/8192.f);
    local += p * logf(p + 1e-10f);
  }
  red[threadIdx.x] = local; __syncthreads();
  for (int off = 128; off; off >>= 1){
    if (threadIdx.x < off) red[threadIdx.x] += red[threadIdx.x + off];
    __syncthreads();
  }
  if (threadIdx.x == 0){
    float mse = redp[0] * (1.f/1048576.f);
    dout[OUT_LOSS] = 1.2f*mse;
    dout[OUT_CMT]  = mse;
    dout[OUT_PERP] = expf(-red[0]);
  }
}

// ---------------- convT1 ----------------
__global__ __launch_bounds__(256) void convt1_kern(const float* __restrict__ qt,
    const float* __restrict__ wt, const float* __restrict__ cb,
    const float* __restrict__ bns, float* __restrict__ d1){
  int gm = blockIdx.x;
  int b = gm >> 1, op0 = (gm & 1) << 6, oc0 = blockIdx.y << 6;
  int tid = threadIdx.x, tx = tid & 15, ty = tid >> 4;
  __shared__ __align__(16) float As[32*68];
  __shared__ __align__(16) float Bs[32*68];
  float acc[4][4] = {};
  for (int k = 0; k < 4; ++k){
    for (int ic0 = 0; ic0 < 128; ic0 += 32){
      #pragma unroll
      for (int rr = 0; rr < 8; ++rr){
        int e = rr*256 + tid; int m = e >> 5, ic = e & 31;
        int op = op0 + m;
        float v = 0.f;
        if (op >= k && (((op - k) & 1) == 0)){
          int ip = (op - k) >> 1;
          v = qt[((size_t)b*64 + ip)*128 + ic0 + ic];
        }
        As[ic*68 + m] = v;
      }
      #pragma unroll
      for (int rr = 0; rr < 8; ++rr){
        int e = rr*256 + tid; int oc = e & 63, ic = e >> 6;
        Bs[ic*68 + oc] = wt[((size_t)k*128 + ic0 + ic)*512 + oc0 + oc];
      }
      __syncthreads();
      #pragma unroll
      for (int kk = 0; kk < 32; ++kk){
        float4 a4 = *(const float4*)&As[kk*68 + ty*4];
        float4 b4 = *(const float4*)&Bs[kk*68 + tx*4];
        FMA44
      }
      __syncthreads();
    }
  }
  #pragma unroll
  for (int i = 0; i < 4; ++i){
    int op = op0 + ty*4 + i;
    #pragma unroll
    for (int jj = 0; jj < 4; ++jj){
      int oc = oc0 + tx*4 + jj;
      float v = acc[i][jj] + cb[oc];
      v = v*bns[DB1S + oc] + bns[DB1T + oc];
      v = v > 0.f ? v : 0.2f*v;
      d1[((size_t)b*128 + op)*512 + oc] = v;
    }
  }
}

// ---------------- convT2 ----------------
__global__ __launch_bounds__(256) void convt2_kern(const float* __restrict__ d1,
    const float* __restrict__ wt, const float* __restrict__ cb,
    const float* __restrict__ bns, float* __restrict__ dec){
  int gm = blockIdx.x;
  int b = gm >> 2, op0 = (gm & 3) << 6, oc0 = blockIdx.y << 6;
  int tid = threadIdx.x, tx = tid & 15, ty = tid >> 4;
  __shared__ __align__(16) float As[32*68];
  __shared__ __align__(16) float Bs[32*68];
  float acc[4][4] = {};
  for (int k = 0; k < 4; ++k){
    for (int ic0 = 0; ic0 < 512; ic0 += 32){
      #pragma unroll
      for (int rr = 0; rr < 8; ++rr){
        int e = rr*256 + tid; int m = e >> 5, ic = e & 31;
        int op = op0 + m;
        float v = 0.f;
        if (op >= k && (((op - k) & 1) == 0)){
          int ip = (op - k) >> 1;
          v = d1[((size_t)b*128 + ip)*512 + ic0 + ic];
        }
        As[ic*68 + m] = v;
      }
      #pragma unroll
      for (int rr = 0; rr < 8; ++rr){
        int e = rr*256 + tid; int oc = e & 63, ic = e >> 6;
        Bs[ic*68 + oc] = wt[((size_t)k*512 + ic0 + ic)*256 + oc0 + oc];
      }
      __syncthreads();
      #pragma unroll
      for (int kk = 0; kk < 32; ++kk){
        float4 a4 = *(const float4*)&As[kk*68 + ty*4];
        float4 b4 = *(const float4*)&Bs[kk*68 + tx*4];
        FMA44
      }
      __syncthreads();
    }
  }
  #pragma unroll
  for (int i = 0; i < 4; ++i){
    int op = op0 + ty*4 + i;
    #pragma unroll
    for (int jj = 0; jj < 4; ++jj){
      int oc = oc0 + tx*4 + jj;
      float v = acc[i][jj] + cb[oc];
      v = v*bns[DB2S + oc] + bns[DB2T + oc];
      v = v > 0.f ? v : 0.2f*v;
      dec[((size_t)b*256 + op)*256 + oc] = v;
    }
  }
}

// ---------------- flush last logits row ----------------
__global__ void copylast_kern(const float* __restrict__ logit1, float* __restrict__ dout){
  int idx = blockIdx.x*256 + threadIdx.x;
  if (idx < 1152) dout[OUT_NR + (size_t)(idx/9)*2304 + 255*9 + (idx % 9)] = logit1[idx];
}

// =====================================================================
extern "C" void kernel_launch(void* const* d_in, const int* in_sizes, int n_in,
                              void* d_out, int out_size, void* d_ws, size_t ws_size,
                              hipStream_t stream){
  (void)in_sizes; (void)n_in; (void)out_size; (void)ws_size;
  const float* note  = (const float*)d_in[0];
  const float* skel  = (const float*)d_in[1];
  const float* se    = (const float*)d_in[2];
  const float* ehw   = (const float*)d_in[3];
  const float* ehb   = (const float*)d_in[4];
  const float* ifw   = (const float*)d_in[5];
  const float* ifb   = (const float*)d_in[6];
  const float* gfwih = (const float*)d_in[7];
  const float* gfwhh = (const float*)d_in[8];
  const float* gfbih = (const float*)d_in[9];
  const float* gfbhh = (const float*)d_in[10];
  const float* gbwih = (const float*)d_in[11];
  const float* gbwhh = (const float*)d_in[12];
  const float* gbbih = (const float*)d_in[13];
  const float* gbbhh = (const float*)d_in[14];
  const float* bn0g  = (const float*)d_in[15];
  const float* bn0b  = (const float*)d_in[16];
  const float* bn0m  = (const float*)d_in[17];
  const float* bn0v  = (const float*)d_in[18];
  const float* c1w   = (const float*)d_in[19];
  const float* c1b   = (const float*)d_in[20];
  const float* bn1g  = (const float*)d_in[21];
  const float* bn1b  = (const float*)d_in[22];
  const float* bn1m  = (const float*)d_in[23];
  const float* bn1v  = (const float*)d_in[24];
  const float* c2w   = (const float*)d_in[25];
  const float* c2b   = (const float*)d_in[26];
  const float* bn2g  = (const float*)d_in[27];
  const float* bn2b  = (const float*)d_in[28];
  const float* bn2m  = (const float*)d_in[29];
  const float* bn2v  = (const float*)d_in[30];
  const float* c3w   = (const float*)d_in[31];
  const float* c3b   = (const float*)d_in[32];
  const float* embed = (const float*)d_in[33];
  const float* ct1w  = (const float*)d_in[34];
  const float* ct1b  = (const float*)d_in[35];
  const float* dbn1g = (const float*)d_in[36];
  const float* dbn1b = (const float*)d_in[37];
  const float* dbn1m = (const float*)d_in[38];
  const float* dbn1v = (const float*)d_in[39];
  const float* ct2w  = (const float*)d_in[40];
  const float* ct2b  = (const float*)d_in[41];
  const float* dbn2g = (const float*)d_in[42];
  const float* dbn2b = (const float*)d_in[43];
  const float* dbn2m = (const float*)d_in[44];
  const float* dbn2v = (const float*)d_in[45];
  const float* dhw   = (const float*)d_in[46];
  const float* dhb   = (const float*)d_in[47];
  const float* g1wih = (const float*)d_in[48];
  const float* g1whh = (const float*)d_in[49];
  const float* g1bih = (const float*)d_in[50];
  const float* g1bhh = (const float*)d_in[51];
  const float* g2wih = (const float*)d_in[52];
  const float* g2whh = (const float*)d_in[53];
  const float* g2bih = (const float*)d_in[54];
  const float* g2bhh = (const float*)d_in[55];
  const float* nfw   = (const float*)d_in[56];
  const float* nfb   = (const float*)d_in[57];
  const float* sr    = (const float*)d_in[58];

  float* ws  = (float*)d_ws;
  float* out = (float*)d_out;
  float* ysp  = ws + O_YS;
  float* bnsp = ws + O_BNS;

  // ---- precompute ----
  trans_kern<<<dim3(2048), dim3(256), 0, stream>>>(c1w, c2w, c3w, ct1w, ct2w, ws);
  bn_kern<<<dim3(11), dim3(256), 0, stream>>>(bn0g,bn0b,bn0m,bn0v, bn1g,bn1b,bn1m,bn1v,
                                              bn2g,bn2b,bn2m,bn2v, dbn1g,dbn1b,dbn1m,dbn1v,
                                              dbn2g,dbn2b,dbn2m,dbn2v, bnsp);
  init_kern<<<dim3(512), dim3(256), 0, stream>>>(se, ehw, ehb, dhw, dhb, ws);
  weff_kern<<<dim3(120), dim3(256), 0, stream>>>(gfwih, gfbih, gbwih, gbbih, ifw, ifb, ws);
  esq_kern<<<dim3(8), dim3(256), 0, stream>>>(embed, ws);
  split_w_kern<<<dim3(1024), dim3(256), 0, stream>>>(gfwhh, gbwhh, ws);

  // ---- encoder bi-GRU, 256 MFMA steps (512-thread blocks) ----
  for (int s = 0; s < 256; ++s){
    enc_step_mfma<<<dim3(256), dim3(512), 0, stream>>>(ws, note, gfbhh, gbbhh, s);
  }

  // ---- conv stack ----
  conv1_kern<<<dim3(256, 8), dim3(256), 0, stream>>>(ysp, ws + O_WT1, c1b, bnsp, ws + O_C1);
  split_w2_kern<<<dim3(2048), dim3(256), 0, stream>>>(g1wih, g1whh, g2wih, g2whh, ws);
  conv2_kern<<<dim3(128, 8), dim3(256), 0, stream>>>(ws + O_C1, ws + O_WT2, c2b, bnsp, ws + O_C2);
  conv3_kern<<<dim3(128, 2), dim3(256), 0, stream>>>(ws + O_C2, ws + O_WT3, c3b, ws + O_ZT);

  // ---- VQ ----
  vq_kern<<<dim3(1024), dim3(256), 0, stream>>>(ws + O_ZT, ws + O_ESQ, embed,
      (int*)(ws + O_IDX), ws + O_HIST, out);
  quant_kern<<<dim3(1024), dim3(256), 0, stream>>>(ws + O_ZT, (const int*)(ws + O_IDX),
      embed, ws + O_QT, ws + O_RED, out);
  perp_kern<<<dim3(1), dim3(256), 0, stream>>>(ws + O_HIST, ws + O_RED, out);

  // ---- decoder convT stack ----
  convt1_kern<<<dim3(256, 8), dim3(256), 0, stream>>>(ws + O_QT, ws + O_WTD1, ct1b, bnsp, ws + O_D1);
  convt2_kern<<<dim3(512, 4), dim3(256), 0, stream>>>(ws + O_D1, ws + O_WTD2, ct2b, bnsp, ws + O_DEC);
  split_dec_kern<<<dim3(2048), dim3(256), 0, stream>>>(ws);

  // ---- autoregressive decoder, 256 steps x (GRU1, GRU2+logits) ----
  for (int i = 0; i < 256; ++i){
    dec_k1_mfma<<<dim3(256), dim3(512), 0, stream>>>(ws, skel, sr, g1wih, g1bih,
        g1bhh, nfb, out, i);
    dec_k2_mfma<<<dim3(256), dim3(512), 0, stream>>>(ws, g2bih, g2bhh, nfw, i);
  }
  copylast_kern<<<dim3(5), dim3(256), 0, stream>>>(ws + O_LOG + 1152, out);
}